// Round 5
// baseline (859.170 us; speedup 1.0000x reference)
//
#include <hip/hip_runtime.h>
#include <cstddef>
#include <cstdint>

namespace {
constexpr int B_ = 8, C_ = 128, H_ = 128, W_ = 128;
constexpr int HW_ = H_ * W_;               // 16384
constexpr size_t CHW_ = (size_t)C_ * HW_;  // 2097152
constexpr int NPIX_ = B_ * HW_;            // 131072
}

typedef __attribute__((ext_vector_type(8))) short bf16x8;
typedef __attribute__((ext_vector_type(4))) float f32x4;
typedef __attribute__((ext_vector_type(8))) unsigned short u16x8;
typedef __attribute__((ext_vector_type(4))) unsigned short u16x4;

__device__ inline unsigned short f2bf(float f) {
  unsigned int u = __float_as_uint(f);
  unsigned int r = u + 0x7FFFu + ((u >> 16) & 1u);
  return (unsigned short)(r >> 16);
}
__device__ inline float bf2f(unsigned short u) {
  return __uint_as_float((unsigned int)u << 16);
}

// ---- conv weight prep: symmetrize, bf16, layout [tap49][grp16][oc128][ic8]
__global__ __launch_bounds__(256) void prep_w_bf16_k(
    const float* __restrict__ Wa, const float* __restrict__ Wb,
    unsigned short* __restrict__ Ta, unsigned short* __restrict__ Tb) {
  int idx = blockIdx.x * 256 + threadIdx.x;  // 802816
  int j = idx & 7;
  int o = (idx >> 3) & 127;
  int g = (idx >> 10) & 15;
  int t = idx >> 14;
  int i = g * 8 + j;
  int ky = t / 7, kx = t - ky * 7;
  size_t oi = ((size_t)(o * 128 + i) * 7 + ky) * 7 + kx;
  size_t io = ((size_t)(i * 128 + o) * 7 + ky) * 7 + kx;
  Ta[idx] = f2bf(0.5f * (Wa[oi] + Wa[io]));
  Tb[idx] = f2bf(0.5f * (Wb[oi] + Wb[io]));
}

// ---- 1x1 weight prep: bf16 fragment layout [s12][f8][lane64][j8] -----------
__global__ __launch_bounds__(256) void prep_apack_k(
    const float* __restrict__ Wg, const float* __restrict__ Wm,
    unsigned short* __restrict__ Ag, unsigned short* __restrict__ Am) {
  int idx = blockIdx.x * 256 + threadIdx.x;  // 49152
  int j = idx & 7;
  int l = (idx >> 3) & 63;
  int f = (idx >> 9) & 7;
  int s = idx >> 12;
  int m = f * 16 + (l & 15);
  int k = s * 32 + (l >> 4) * 8 + j;
  Ag[idx] = f2bf(Wg[m * 384 + k]);
  Am[idx] = f2bf(Wm[m * 384 + k]);
}

// ---- row sums of the 1x1 weights, on bf16-rounded values (LN folding) ------
__global__ void rowsum_k(const float* __restrict__ Wg,
                         const float* __restrict__ Wm, float* __restrict__ rs) {
  int t = threadIdx.x;
  const float* src = (t < 128) ? Wg : Wm;
  int row = t & 127;
  float s = 0.f;
  for (int i = 0; i < 384; ++i) s += bf2f(f2bf(src[row * 384 + i]));
  rs[t] = s;
}

// ---- LN stats over [h_exc,h_inh,ff] + bf16 copies + partial sums over
// ---- (h_exc,h_inh) for the later g2 LN ------------------------------------
__global__ __launch_bounds__(256) void stats3_cvt_k(
    const float* __restrict__ t0, const float* __restrict__ t1,
    const float* __restrict__ t2, float* __restrict__ mu_o,
    float* __restrict__ inv_o, float* __restrict__ ps12,
    float* __restrict__ pq12, unsigned short* __restrict__ o0,
    unsigned short* __restrict__ o1, unsigned short* __restrict__ o2) {
  int q = blockIdx.x * 256 + threadIdx.x;
  int b = q >> 14, p = q & (HW_ - 1);
  size_t base = (size_t)b * CHW_ + p;
  float s = 0.f, s2 = 0.f;
  for (int c = 0; c < C_; ++c) {
    size_t a = base + (size_t)c * HW_;
    float v = t0[a]; s += v; s2 = fmaf(v, v, s2); o0[a] = f2bf(v);
  }
  for (int c = 0; c < C_; ++c) {
    size_t a = base + (size_t)c * HW_;
    float v = t1[a]; s += v; s2 = fmaf(v, v, s2); o1[a] = f2bf(v);
  }
  ps12[q] = s;
  pq12[q] = s2;
  for (int c = 0; c < C_; ++c) {
    size_t a = base + (size_t)c * HW_;
    float v = t2[a]; s += v; s2 = fmaf(v, v, s2); o2[a] = f2bf(v);
  }
  float m = s * (1.f / 384.f);
  float var = s2 * (1.f / 384.f) - m * m;
  mu_o[q] = m;
  inv_o[q] = rsqrtf(var + 1e-5f);
}

// ---- MFMA 1x1-conv gate GEMM: M=128, K=384, N=16384/batch ------------------
template <int FINAL>
__global__ __launch_bounds__(256) void gemm_mfma_k(
    const unsigned short* __restrict__ Apack, const float* __restrict__ rowsum,
    const float* __restrict__ bias, const unsigned short* __restrict__ B0,
    const unsigned short* __restrict__ B1, const unsigned short* __restrict__ B2,
    const float* __restrict__ mu, const float* __restrict__ inv,
    const float* __restrict__ mult_f32, unsigned short* __restrict__ out_cl,
    const unsigned short* __restrict__ c2raw, const float* __restrict__ muc,
    const float* __restrict__ invc, const unsigned short* __restrict__ inh_bf,
    const float* __restrict__ h_exc, const float* __restrict__ c2g,
    const float* __restrict__ c2b, const float* __restrict__ kap,
    const float* __restrict__ omg, float* __restrict__ out_f32) {
  int b = blockIdx.y;
  int tid = threadIdx.x;
  int lane = tid & 63, wid = tid >> 6;
  int l15 = lane & 15, kg = lane >> 4;
  int n0 = blockIdx.x * 128 + wid * 32;
  size_t bofs = (size_t)b * CHW_;
  f32x4 acc[8][2] = {};
  for (int s = 0; s < 12; ++s) {
    const unsigned short* src = (s < 4) ? B0 : ((s < 8) ? B1 : B2);
    const unsigned short* bp =
        src + bofs + (size_t)((s & 3) * 32 + kg * 8) * HW_ + n0 + l15;
    bf16x8 bfr[2];
#pragma unroll
    for (int nf = 0; nf < 2; ++nf) {
      const unsigned short* qp = bp + nf * 16;
      bf16x8 v;
      v[0] = (short)qp[0];
      v[1] = (short)qp[HW_];
      v[2] = (short)qp[2 * HW_];
      v[3] = (short)qp[3 * HW_];
      v[4] = (short)qp[4 * HW_];
      v[5] = (short)qp[5 * HW_];
      v[6] = (short)qp[6 * HW_];
      v[7] = (short)qp[7 * HW_];
      bfr[nf] = v;
    }
    const bf16x8* ap = (const bf16x8*)(Apack + ((size_t)(s * 8) * 64 + lane) * 8);
#pragma unroll
    for (int f = 0; f < 8; ++f) {
      bf16x8 afr = ap[f * 64];
#pragma unroll
      for (int nf = 0; nf < 2; ++nf)
        acc[f][nf] = __builtin_amdgcn_mfma_f32_16x16x32_bf16(afr, bfr[nf],
                                                             acc[f][nf], 0, 0, 0);
    }
  }
#pragma unroll
  for (int nf = 0; nf < 2; ++nf) {
    int n = n0 + nf * 16 + l15;
    int qpix = b * HW_ + n;
    float muv = mu[qpix], invv = inv[qpix];
    if (!FINAL) {
#pragma unroll
      for (int mf = 0; mf < 8; ++mf) {
        int m0 = mf * 16 + kg * 4;
        f32x4 rs4 = *(const f32x4*)(rowsum + m0);
        f32x4 bi4 = *(const f32x4*)(bias + m0);
        u16x4 st;
#pragma unroll
        for (int j = 0; j < 4; ++j) {
          float val = invv * (acc[mf][nf][j] - muv * rs4[j]) + bi4[j];
          float g = 1.f / (1.f + __expf(-val));
          float h = mult_f32[bofs + (size_t)(m0 + j) * HW_ + n];
          st[j] = f2bf(h * g);
        }
        *(u16x4*)(out_cl + (size_t)qpix * 128 + m0) = st;
      }
    } else {
      float mcv = muc[qpix], icv = invc[qpix];
#pragma unroll
      for (int mf = 0; mf < 8; ++mf) {
        int m0 = mf * 16 + kg * 4;
        f32x4 rs4 = *(const f32x4*)(rowsum + m0);
        f32x4 bi4 = *(const f32x4*)(bias + m0);
        f32x4 g4 = *(const f32x4*)(c2g + m0);
        f32x4 b4 = *(const f32x4*)(c2b + m0);
        f32x4 k4 = *(const f32x4*)(kap + m0);
        f32x4 o4 = *(const f32x4*)(omg + m0);
#pragma unroll
        for (int j = 0; j < 4; ++j) {
          size_t idx = bofs + (size_t)(m0 + j) * HW_ + n;
          float val = invv * (acc[mf][nf][j] - muv * rs4[j]) + bi4[j];
          float g2 = 1.f / (1.f + __expf(-val));
          float c2 = (bf2f(c2raw[idx]) - mcv) * icv * g4[j] + b4[j];
          float iv = bf2f(inh_bf[idx]);
          float ht =
              fmaxf(k4[j] * (iv + c2) + fmaxf(o4[j], 0.f) * (iv * c2), 0.f);
          out_f32[idx] = (1.f - g2) * h_exc[idx] + g2 * ht;
        }
      }
    }
  }
}

// ---- 7x7 SAME conv via 16x16x32 MFMA ---------------------------------------
// Weights direct-from-global (register double-buffered across kx);
// 3-slot input-row ring (1 barrier/ky); fused per-pixel LN stats.
// Block 256 = 4 waves; tile 128oc x 2 rows x 128 px.
// Wave (wm = oc-half, wn = row): 64oc x 128px; acc = 4mf x 8nf x f32x4.
__global__ __launch_bounds__(256, 2) void conv7_mfma_k(
    const unsigned short* __restrict__ in_cl,
    const unsigned short* __restrict__ Wp, unsigned short* __restrict__ out,
    float* __restrict__ mu_o, float* __restrict__ inv_o) {
  __shared__ short in_s[3][4][138][8];  // 26496 B, 3-row ring
  __shared__ float red_s[2][2][128];
  __shared__ float red_q[2][2][128];
  int b = blockIdx.x >> 6;
  int y0 = (blockIdx.x & 63) * 2;
  int tid = threadIdx.x;
  int lane = tid & 63, wid = tid >> 6;
  int wm = wid >> 1, wn = wid & 1;
  int l15 = lane & 15, kg = lane >> 4;
  const unsigned short* inb = in_cl + (size_t)b * CHW_;
  // staging chunks: u in [0,536): px = u>>2 (134 px window), g = u&3
  int pg[3], ppx[3];
#pragma unroll
  for (int it = 0; it < 3; ++it) {
    int u = tid + it * 256;
    ppx[it] = u >> 2;
    pg[it] = u & 3;
  }
  // per-lane weight base: [tap][g16][oc128][ic8]; g = c4*4 + kg
  const unsigned short* wlane = Wp + ((size_t)kg * 128 + wm * 64 + l15) * 8;
  f32x4 acc[4][8] = {};
  u16x8 pf[3];
  for (int c4 = 0; c4 < 4; ++c4) {
    const unsigned short* wc4 = wlane + (size_t)c4 * 4 * 128 * 8;
    __syncthreads();  // previous c4 readers done with all slots
    // prologue: stage rows y0-3, y0-2 directly
#pragma unroll
    for (int r = 0; r < 2; ++r) {
      int y = y0 - 3 + r;
      int sl = (y0 + r) % 3;
#pragma unroll
      for (int it = 0; it < 3; ++it) {
        int u = tid + it * 256;
        if (u < 536) {
          int x = ppx[it] - 3;
          u16x8 v = {};
          if (x >= 0 && x < 128 && y >= 0)
            v = *(const u16x8*)(inb + ((size_t)(y * 128 + x) * 128 + c4 * 32 +
                                       pg[it] * 8));
          *(u16x8*)(&in_s[sl][pg[it]][ppx[it]][0]) = v;
        }
      }
    }
    // issue prefetch of row y0-1 into registers
    {
      int y = y0 - 1;
#pragma unroll
      for (int it = 0; it < 3; ++it) {
        int u = tid + it * 256;
        pf[it] = u16x8{};
        if (u < 536) {
          int x = ppx[it] - 3;
          if (x >= 0 && x < 128 && y >= 0)
            pf[it] = *(const u16x8*)(inb + ((size_t)(y * 128 + x) * 128 +
                                            c4 * 32 + pg[it] * 8));
        }
      }
    }
    __syncthreads();  // prologue rows visible
    for (int ky = 0; ky < 7; ++ky) {
      if (ky) __syncthreads();  // prior reads done before ring overwrite
      // commit prefetched row (y0+ky-1) to its slot
      if (ky < 6) {
        int slC = (y0 + ky + 2) % 3;
#pragma unroll
        for (int it = 0; it < 3; ++it) {
          int u = tid + it * 256;
          if (u < 536) *(u16x8*)(&in_s[slC][pg[it]][ppx[it]][0]) = pf[it];
        }
      }
      // issue prefetch for row y0+ky (committed next ky)
      if (ky < 5) {
        int y = y0 + ky;
#pragma unroll
        for (int it = 0; it < 3; ++it) {
          int u = tid + it * 256;
          pf[it] = u16x8{};
          if (u < 536) {
            int x = ppx[it] - 3;
            if (x >= 0 && x < 128 && y < 128)
              pf[it] = *(const u16x8*)(inb + ((size_t)(y * 128 + x) * 128 +
                                              c4 * 32 + pg[it] * 8));
          }
        }
      }
      // compute: reads slots (y0+ky+wn)%3 — committed >=1 barrier ago
      int sl = (y0 + ky + wn) % 3;
      const short* rowp = &in_s[sl][kg][l15][0];
      const unsigned short* wky = wc4 + (size_t)(ky * 7) * 16384;
      bf16x8 afr[2][4], bfr[8];
#pragma unroll
      for (int mf = 0; mf < 4; ++mf)
        afr[0][mf] = *(const bf16x8*)(wky + mf * 128);
#pragma unroll
      for (int kx = 0; kx < 7; ++kx) {
        int cur = kx & 1, nxt = cur ^ 1;
        if (kx < 6) {
#pragma unroll
          for (int mf = 0; mf < 4; ++mf)
            afr[nxt][mf] = *(const bf16x8*)(wky + (kx + 1) * 16384 + mf * 128);
        }
#pragma unroll
        for (int nf = 0; nf < 8; ++nf)
          bfr[nf] = *(const bf16x8*)(rowp + (nf * 16 + kx) * 8);
#pragma unroll
        for (int nf = 0; nf < 8; ++nf)
#pragma unroll
          for (int mf = 0; mf < 4; ++mf)
            acc[mf][nf] = __builtin_amdgcn_mfma_f32_16x16x32_bf16(
                afr[cur][mf], bfr[nf], acc[mf][nf], 0, 0, 0);
      }
    }
  }
  // epilogue: store bf16 NCHW + fused per-pixel LN stats
  int y = y0 + wn;
  size_t ob = (size_t)b * CHW_ + (size_t)y * 128;
#pragma unroll
  for (int nf = 0; nf < 8; ++nf) {
    int x = nf * 16 + l15;
    float s = 0.f, qq = 0.f;
#pragma unroll
    for (int mf = 0; mf < 4; ++mf) {
#pragma unroll
      for (int j = 0; j < 4; ++j) {
        int oc = wm * 64 + mf * 16 + kg * 4 + j;
        unsigned short bv = f2bf(acc[mf][nf][j]);
        float vr = bf2f(bv);
        s += vr;
        qq = fmaf(vr, vr, qq);
        out[ob + (size_t)oc * HW_ + x] = bv;
      }
    }
    s += __shfl_xor(s, 16);
    qq += __shfl_xor(qq, 16);
    s += __shfl_xor(s, 32);
    qq += __shfl_xor(qq, 32);
    if (lane < 16) {
      red_s[wm][wn][x] = s;
      red_q[wm][wn][x] = qq;
    }
  }
  __syncthreads();
  {
    int wn2 = tid >> 7, x2 = tid & 127;
    float s = red_s[0][wn2][x2] + red_s[1][wn2][x2];
    float qq = red_q[0][wn2][x2] + red_q[1][wn2][x2];
    float m = s * (1.f / 128.f);
    float var = qq * (1.f / 128.f) - m * m;
    int q = b * HW_ + (y0 + wn2) * 128 + x2;
    mu_o[q] = m;
    inv_o[q] = rsqrtf(var + 1e-5f);
  }
}

// ---- inhibited = relu(ff - relu((sig(alpha)*h_inh+mu)*LN(c1))) --------------
// + fused g2 LN stats (own sums + precomputed h_exc/h_inh partials)
__global__ __launch_bounds__(256) void inhibit_k(
    const unsigned short* __restrict__ c1_raw_bf, const float* __restrict__ ff,
    const unsigned short* __restrict__ hinh_bf, const float* __restrict__ mu_s,
    const float* __restrict__ inv_s, const float* __restrict__ ps12,
    const float* __restrict__ pq12, const float* __restrict__ alpha,
    const float* __restrict__ mu_p, const float* __restrict__ gamma,
    const float* __restrict__ beta, unsigned short* __restrict__ out_nchw,
    unsigned short* __restrict__ out_cl, float* __restrict__ mu2_o,
    float* __restrict__ inv2_o) {
  __shared__ unsigned short tile[32 * 136];
  __shared__ float s8[8][32];
  __shared__ float q8[8][32];
  int blk = blockIdx.x;
  int b = blk >> 9;
  int p0 = (blk & 511) * 32;
  int t = threadIdx.x;
  int px = t & 31, cq = t >> 5;
  int q = b * HW_ + p0 + px;
  float muv = mu_s[q], invv = inv_s[q];
  size_t pixbase = (size_t)b * CHW_ + p0 + px;
  float sp = 0.f, qp = 0.f;
  for (int ci = 0; ci < 16; ++ci) {
    int c = cq * 16 + ci;
    size_t idx = pixbase + (size_t)c * HW_;
    float c1 = (bf2f(c1_raw_bf[idx]) - muv) * invv * gamma[c] + beta[c];
    float a = 1.f / (1.f + __expf(-alpha[c]));
    float r = fmaxf((a * bf2f(hinh_bf[idx]) + mu_p[c]) * c1, 0.f);
    float v = fmaxf(ff[idx] - r, 0.f);
    unsigned short bv = f2bf(v);
    float vr = bf2f(bv);
    sp += vr;
    qp = fmaf(vr, vr, qp);
    out_nchw[idx] = bv;
    tile[px * 136 + c] = bv;
  }
  s8[cq][px] = sp;
  q8[cq][px] = qp;
  __syncthreads();
#pragma unroll
  for (int pass = 0; pass < 2; ++pass) {
    int u = pass * 256 + t;
    int ppx = u >> 4, cg = u & 15;
    u16x8 v = *(const u16x8*)(tile + ppx * 136 + cg * 8);
    *(u16x8*)(out_cl + (size_t)(b * HW_ + p0 + ppx) * 128 + cg * 8) = v;
  }
  if (t < 32) {
    float s = 0.f, qsum = 0.f;
#pragma unroll
    for (int k = 0; k < 8; ++k) {
      s += s8[k][t];
      qsum += q8[k][t];
    }
    int qn = b * HW_ + p0 + t;
    s += ps12[qn];
    qsum += pq12[qn];
    float m = s * (1.f / 384.f);
    float var = qsum * (1.f / 384.f) - m * m;
    mu2_o[qn] = m;
    inv2_o[qn] = rsqrtf(var + 1e-5f);
  }
}

extern "C" void kernel_launch(void* const* d_in, const int* in_sizes, int n_in,
                              void* d_out, int out_size, void* d_ws,
                              size_t ws_size, hipStream_t stream) {
  const float* ff     = (const float*)d_in[0];
  const float* h_exc  = (const float*)d_in[1];
  const float* h_inh  = (const float*)d_in[2];
  const float* W_gain = (const float*)d_in[3];
  const float* b_gain = (const float*)d_in[4];
  const float* W_mix  = (const float*)d_in[5];
  const float* b_mix  = (const float*)d_in[6];
  const float* W_inh  = (const float*)d_in[7];
  const float* W_exc  = (const float*)d_in[8];
  const float* alpha  = (const float*)d_in[9];
  const float* mu_p   = (const float*)d_in[10];
  const float* kappa  = (const float*)d_in[11];
  const float* omega  = (const float*)d_in[12];
  const float* c1_g   = (const float*)d_in[13];
  const float* c1_b   = (const float*)d_in[14];
  const float* c2_g   = (const float*)d_in[15];
  const float* c2_b   = (const float*)d_in[16];

  float* w = (float*)d_ws;
  unsigned short* Wp_inh = (unsigned short*)w;  w += 401408;
  unsigned short* Wp_exc = (unsigned short*)w;  w += 401408;
  unsigned short* Ag     = (unsigned short*)w;  w += 24576;
  unsigned short* Am     = (unsigned short*)w;  w += 24576;
  float* rs     = w;  w += 256;
  float* mu1    = w;  w += NPIX_;
  float* inv1   = w;  w += NPIX_;
  float* mu_c1  = w;  w += NPIX_;
  float* inv_c1 = w;  w += NPIX_;
  float* mu2    = w;  w += NPIX_;
  float* inv2   = w;  w += NPIX_;
  float* mu_c2  = w;  w += NPIX_;
  float* inv_c2 = w;  w += NPIX_;
  float* ps12   = w;  w += NPIX_;
  float* pq12   = w;  w += NPIX_;
  unsigned short* exc_bf   = (unsigned short*)w;  w += 8388608;
  unsigned short* hinh_bf  = (unsigned short*)w;  w += 8388608;
  unsigned short* ffinh_bf = (unsigned short*)w;  w += 8388608;  // ff, then inhibited
  unsigned short* conv_bf  = (unsigned short*)w;  w += 8388608;  // c1_raw, then c2_raw

  unsigned short* gated_cl = (unsigned short*)d_out;
  unsigned short* inh_cl   = (unsigned short*)d_out + (size_t)16777216;

  prep_w_bf16_k<<<3136, 256, 0, stream>>>(W_inh, W_exc, Wp_inh, Wp_exc);
  prep_apack_k<<<192, 256, 0, stream>>>(W_gain, W_mix, Ag, Am);
  rowsum_k<<<1, 256, 0, stream>>>(W_gain, W_mix, rs);

  // g1 LN stats + bf16 copies + (h_exc,h_inh) partial sums for g2
  stats3_cvt_k<<<512, 256, 0, stream>>>(h_exc, h_inh, ff, mu1, inv1, ps12,
                                        pq12, exc_bf, hinh_bf, ffinh_bf);
  // gated = h_exc * g1  (bf16 channels-last into d_out lo)
  {
    dim3 g(128, 8);
    gemm_mfma_k<0><<<g, 256, 0, stream>>>(
        Ag, rs, b_gain, exc_bf, hinh_bf, ffinh_bf, mu1, inv1, h_exc, gated_cl,
        nullptr, nullptr, nullptr, nullptr, nullptr, nullptr, nullptr, nullptr,
        nullptr, nullptr);
  }
  // c1 = sym_conv(gated) + fused LN stats
  conv7_mfma_k<<<512, 256, 0, stream>>>(gated_cl, Wp_inh, conv_bf, mu_c1,
                                        inv_c1);
  // inhibited + fused g2 LN stats
  inhibit_k<<<4096, 256, 0, stream>>>(conv_bf, ff, hinh_bf, mu_c1, inv_c1,
                                      ps12, pq12, alpha, mu_p, c1_g, c1_b,
                                      ffinh_bf, inh_cl, mu2, inv2);
  // c2 = sym_conv(inhibited) + fused LN stats
  conv7_mfma_k<<<512, 256, 0, stream>>>(inh_cl, Wp_exc, conv_bf, mu_c2,
                                        inv_c2);
  // g2 gemm + fused final mix -> d_out f32 NCHW
  {
    dim3 g(128, 8);
    gemm_mfma_k<1><<<g, 256, 0, stream>>>(
        Am, rs + 128, b_mix, ffinh_bf, exc_bf, hinh_bf, mu2, inv2, nullptr,
        nullptr, conv_bf, mu_c2, inv_c2, ffinh_bf, h_exc, c2_g, c2_b, kappa,
        omega, (float*)d_out);
  }
}

// Round 6
// 835.774 us; speedup vs baseline: 1.0280x; 1.0280x over previous
//
#include <hip/hip_runtime.h>
#include <cstddef>
#include <cstdint>

namespace {
constexpr int B_ = 8, C_ = 128, H_ = 128, W_ = 128;
constexpr int HW_ = H_ * W_;               // 16384
constexpr size_t CHW_ = (size_t)C_ * HW_;  // 2097152
constexpr int NPIX_ = B_ * HW_;            // 131072
}

typedef __attribute__((ext_vector_type(8))) short bf16x8;
typedef __attribute__((ext_vector_type(4))) float f32x4;
typedef __attribute__((ext_vector_type(8))) unsigned short u16x8;
typedef __attribute__((ext_vector_type(4))) unsigned short u16x4;

__device__ inline unsigned short f2bf(float f) {
  unsigned int u = __float_as_uint(f);
  unsigned int r = u + 0x7FFFu + ((u >> 16) & 1u);
  return (unsigned short)(r >> 16);
}
__device__ inline float bf2f(unsigned short u) {
  return __uint_as_float((unsigned int)u << 16);
}

// ---- conv weight prep: symmetrize, bf16, layout [tap49][grp16][oc128][ic8]
__global__ __launch_bounds__(256) void prep_w_bf16_k(
    const float* __restrict__ Wa, const float* __restrict__ Wb,
    unsigned short* __restrict__ Ta, unsigned short* __restrict__ Tb) {
  int idx = blockIdx.x * 256 + threadIdx.x;  // 802816
  int j = idx & 7;
  int o = (idx >> 3) & 127;
  int g = (idx >> 10) & 15;
  int t = idx >> 14;
  int i = g * 8 + j;
  int ky = t / 7, kx = t - ky * 7;
  size_t oi = ((size_t)(o * 128 + i) * 7 + ky) * 7 + kx;
  size_t io = ((size_t)(i * 128 + o) * 7 + ky) * 7 + kx;
  Ta[idx] = f2bf(0.5f * (Wa[oi] + Wa[io]));
  Tb[idx] = f2bf(0.5f * (Wb[oi] + Wb[io]));
}

// ---- 1x1 weight prep: bf16 fragment layout [s12][f8][lane64][j8] -----------
__global__ __launch_bounds__(256) void prep_apack_k(
    const float* __restrict__ Wg, const float* __restrict__ Wm,
    unsigned short* __restrict__ Ag, unsigned short* __restrict__ Am) {
  int idx = blockIdx.x * 256 + threadIdx.x;  // 49152
  int j = idx & 7;
  int l = (idx >> 3) & 63;
  int f = (idx >> 9) & 7;
  int s = idx >> 12;
  int m = f * 16 + (l & 15);
  int k = s * 32 + (l >> 4) * 8 + j;
  Ag[idx] = f2bf(Wg[m * 384 + k]);
  Am[idx] = f2bf(Wm[m * 384 + k]);
}

// ---- row sums of the 1x1 weights, on bf16-rounded values (LN folding) ------
__global__ void rowsum_k(const float* __restrict__ Wg,
                         const float* __restrict__ Wm, float* __restrict__ rs) {
  int t = threadIdx.x;
  const float* src = (t < 128) ? Wg : Wm;
  int row = t & 127;
  float s = 0.f;
  for (int i = 0; i < 384; ++i) s += bf2f(f2bf(src[row * 384 + i]));
  rs[t] = s;
}

// ---- LN stats over [h_exc,h_inh,ff] + bf16 copies + partial sums over
// ---- (h_exc,h_inh) for the later g2 LN ------------------------------------
__global__ __launch_bounds__(256) void stats3_cvt_k(
    const float* __restrict__ t0, const float* __restrict__ t1,
    const float* __restrict__ t2, float* __restrict__ mu_o,
    float* __restrict__ inv_o, float* __restrict__ ps12,
    float* __restrict__ pq12, unsigned short* __restrict__ o0,
    unsigned short* __restrict__ o1, unsigned short* __restrict__ o2) {
  int q = blockIdx.x * 256 + threadIdx.x;
  int b = q >> 14, p = q & (HW_ - 1);
  size_t base = (size_t)b * CHW_ + p;
  float s = 0.f, s2 = 0.f;
  for (int c = 0; c < C_; ++c) {
    size_t a = base + (size_t)c * HW_;
    float v = t0[a]; s += v; s2 = fmaf(v, v, s2); o0[a] = f2bf(v);
  }
  for (int c = 0; c < C_; ++c) {
    size_t a = base + (size_t)c * HW_;
    float v = t1[a]; s += v; s2 = fmaf(v, v, s2); o1[a] = f2bf(v);
  }
  ps12[q] = s;
  pq12[q] = s2;
  for (int c = 0; c < C_; ++c) {
    size_t a = base + (size_t)c * HW_;
    float v = t2[a]; s += v; s2 = fmaf(v, v, s2); o2[a] = f2bf(v);
  }
  float m = s * (1.f / 384.f);
  float var = s2 * (1.f / 384.f) - m * m;
  mu_o[q] = m;
  inv_o[q] = rsqrtf(var + 1e-5f);
}

// ---- MFMA 1x1-conv gate GEMM: M=128, K=384, N=16384/batch ------------------
// FINAL=0: out = bf16-cl gated = h_exc * sigmoid(LNfold)
// FINAL=1: out = f32 NCHW h_new = (1-g2)*h_exc + g2*h_tilde(c2, inh)
template <int FINAL>
__global__ __launch_bounds__(256) void gemm_mfma_k(
    const unsigned short* __restrict__ Apack, const float* __restrict__ rowsum,
    const float* __restrict__ bias, const unsigned short* __restrict__ B0,
    const unsigned short* __restrict__ B1, const unsigned short* __restrict__ B2,
    const float* __restrict__ mu, const float* __restrict__ inv,
    const unsigned short* __restrict__ mult_bf, unsigned short* __restrict__ out_cl,
    const unsigned short* __restrict__ c2raw, const float* __restrict__ muc,
    const float* __restrict__ invc, const unsigned short* __restrict__ inh_bf,
    const unsigned short* __restrict__ hexc_bf, const float* __restrict__ c2g,
    const float* __restrict__ c2b, const float* __restrict__ kap,
    const float* __restrict__ omg, float* __restrict__ out_f32) {
  int b = blockIdx.y;
  int tid = threadIdx.x;
  int lane = tid & 63, wid = tid >> 6;
  int l15 = lane & 15, kg = lane >> 4;
  int n0 = blockIdx.x * 128 + wid * 32;
  size_t bofs = (size_t)b * CHW_;
  f32x4 acc[8][2] = {};
  for (int s = 0; s < 12; ++s) {
    const unsigned short* src = (s < 4) ? B0 : ((s < 8) ? B1 : B2);
    const unsigned short* bp =
        src + bofs + (size_t)((s & 3) * 32 + kg * 8) * HW_ + n0 + l15;
    bf16x8 bfr[2];
#pragma unroll
    for (int nf = 0; nf < 2; ++nf) {
      const unsigned short* qp = bp + nf * 16;
      bf16x8 v;
      v[0] = (short)qp[0];
      v[1] = (short)qp[HW_];
      v[2] = (short)qp[2 * HW_];
      v[3] = (short)qp[3 * HW_];
      v[4] = (short)qp[4 * HW_];
      v[5] = (short)qp[5 * HW_];
      v[6] = (short)qp[6 * HW_];
      v[7] = (short)qp[7 * HW_];
      bfr[nf] = v;
    }
    const bf16x8* ap = (const bf16x8*)(Apack + ((size_t)(s * 8) * 64 + lane) * 8);
#pragma unroll
    for (int f = 0; f < 8; ++f) {
      bf16x8 afr = ap[f * 64];
#pragma unroll
      for (int nf = 0; nf < 2; ++nf)
        acc[f][nf] = __builtin_amdgcn_mfma_f32_16x16x32_bf16(afr, bfr[nf],
                                                             acc[f][nf], 0, 0, 0);
    }
  }
#pragma unroll
  for (int nf = 0; nf < 2; ++nf) {
    int n = n0 + nf * 16 + l15;
    int qpix = b * HW_ + n;
    float muv = mu[qpix], invv = inv[qpix];
    if (!FINAL) {
#pragma unroll
      for (int mf = 0; mf < 8; ++mf) {
        int m0 = mf * 16 + kg * 4;
        f32x4 rs4 = *(const f32x4*)(rowsum + m0);
        f32x4 bi4 = *(const f32x4*)(bias + m0);
        u16x4 st;
#pragma unroll
        for (int j = 0; j < 4; ++j) {
          float val = invv * (acc[mf][nf][j] - muv * rs4[j]) + bi4[j];
          float g = 1.f / (1.f + __expf(-val));
          float h = bf2f(mult_bf[bofs + (size_t)(m0 + j) * HW_ + n]);
          st[j] = f2bf(h * g);
        }
        *(u16x4*)(out_cl + (size_t)qpix * 128 + m0) = st;
      }
    } else {
      float mcv = muc[qpix], icv = invc[qpix];
#pragma unroll
      for (int mf = 0; mf < 8; ++mf) {
        int m0 = mf * 16 + kg * 4;
        f32x4 rs4 = *(const f32x4*)(rowsum + m0);
        f32x4 bi4 = *(const f32x4*)(bias + m0);
        f32x4 g4 = *(const f32x4*)(c2g + m0);
        f32x4 b4 = *(const f32x4*)(c2b + m0);
        f32x4 k4 = *(const f32x4*)(kap + m0);
        f32x4 o4 = *(const f32x4*)(omg + m0);
#pragma unroll
        for (int j = 0; j < 4; ++j) {
          size_t idx = bofs + (size_t)(m0 + j) * HW_ + n;
          float val = invv * (acc[mf][nf][j] - muv * rs4[j]) + bi4[j];
          float g2 = 1.f / (1.f + __expf(-val));
          float c2 = (bf2f(c2raw[idx]) - mcv) * icv * g4[j] + b4[j];
          float iv = bf2f(inh_bf[idx]);
          float ht =
              fmaxf(k4[j] * (iv + c2) + fmaxf(o4[j], 0.f) * (iv * c2), 0.f);
          out_f32[idx] = (1.f - g2) * bf2f(hexc_bf[idx]) + g2 * ht;
        }
      }
    }
  }
}

// ---- 7x7 SAME conv via MFMA bf16 (round-3 structure) + fused LN stats ------
// in_cl: [B][H][W][128] bf16. Wp: [49][16][128][8] bf16. out: NCHW bf16.
// Block: 512 thr = 8 waves; tile 128oc x (2 rows x 128 px). Wave: 64oc x 64px.
__global__ __launch_bounds__(512, 4) void conv7_mfma_k(
    const unsigned short* __restrict__ in_cl,
    const unsigned short* __restrict__ Wp, unsigned short* __restrict__ out,
    float* __restrict__ mu_o, float* __restrict__ inv_o) {
  __shared__ short w_s[7 * 4 * 128 * 8];   // [kx][g][oc][8] 57344 B
  __shared__ short in_s[2 * 4 * 136 * 8];  // [r][g][xi][8]  17408 B
  int b = blockIdx.x >> 6;
  int y0 = (blockIdx.x & 63) * 2;
  int tid = threadIdx.x;
  int lane = tid & 63;
  int wid = tid >> 6;
  int wm = wid >> 2;  // 0..1 -> oc half
  int wn = wid & 3;   // 0..3 -> (row, px-half)
  int l15 = lane & 15, kg = lane >> 4;
  f32x4 acc[4][4] = {};
  for (int ky = 0; ky < 7; ++ky) {
    int ybase = y0 + ky - 3;
    for (int c4 = 0; c4 < 4; ++c4) {
      __syncthreads();
      // stage weights: 7 taps x 8KB, contiguous copies
#pragma unroll
      for (int kx = 0; kx < 7; ++kx) {
        u16x8 wv = *(const u16x8*)(Wp + (size_t)(ky * 7 + kx) * 16384 +
                                   c4 * 4096 + tid * 8);
        *(u16x8*)(w_s + kx * 4096 + tid * 8) = wv;
      }
      // stage input: 2 rows x 4 kgrp x 136 x (8 ic), zero-padded halo
      for (int u = tid; u < 1088; u += 512) {
        int r = u / 544;
        int rem = u - r * 544;
        int g = rem / 136;
        int xi = rem - g * 136;
        int x = xi - 3;
        int y = ybase + r;
        u16x8 v = {};
        if (x >= 0 && x < 128 && y >= 0 && y < 128)
          v = *(const u16x8*)(in_cl + ((size_t)((b * 128 + y) * 128 + x) * 128 +
                                       c4 * 32 + g * 8));
        *(u16x8*)(in_s + u * 8) = v;
      }
      __syncthreads();
      for (int kx = 0; kx < 7; ++kx) {
        bf16x8 bfr[4], afr[4];
#pragma unroll
        for (int nf = 0; nf < 4; ++nf) {
          int xi = (wn & 1) * 64 + nf * 16 + l15 + kx;
          bfr[nf] = *(const bf16x8*)(in_s + (((wn >> 1) * 4 + kg) * 136 + xi) * 8);
        }
#pragma unroll
        for (int mf = 0; mf < 4; ++mf) {
          int oc = wm * 64 + mf * 16 + l15;
          afr[mf] = *(const bf16x8*)(w_s + ((kx * 4 + kg) * 128 + oc) * 8);
        }
#pragma unroll
        for (int mf = 0; mf < 4; ++mf)
#pragma unroll
          for (int nf = 0; nf < 4; ++nf)
            acc[mf][nf] = __builtin_amdgcn_mfma_f32_16x16x32_bf16(
                afr[mf], bfr[nf], acc[mf][nf], 0, 0, 0);
      }
    }
  }
  // ---- epilogue: bf16 NCHW store + fused per-pixel LN stats ----
  __syncthreads();  // all compute done; in_s reusable as reduction scratch
  float* red = (float*)in_s;  // red_s = red[0..511], red_q = red[512..1023]
  int row = wn >> 1;
  int y = y0 + row;
  int xb = (wn & 1) * 64;
  size_t ob = (size_t)b * CHW_ + (size_t)y * 128;
#pragma unroll
  for (int nf = 0; nf < 4; ++nf) {
    int x = xb + nf * 16 + l15;
    float s = 0.f, qq = 0.f;
#pragma unroll
    for (int mf = 0; mf < 4; ++mf) {
      int oc = wm * 64 + mf * 16 + kg * 4;
#pragma unroll
      for (int j = 0; j < 4; ++j) {
        unsigned short bv = f2bf(acc[mf][nf][j]);
        float vr = bf2f(bv);
        s += vr;
        qq = fmaf(vr, vr, qq);
        out[ob + (size_t)(oc + j) * HW_ + x] = bv;
      }
    }
    s += __shfl_xor(s, 16);
    qq += __shfl_xor(qq, 16);
    s += __shfl_xor(s, 32);
    qq += __shfl_xor(qq, 32);
    if (kg == 0) {
      red[(wm * 2 + row) * 128 + x] = s;
      red[512 + (wm * 2 + row) * 128 + x] = qq;
    }
  }
  __syncthreads();
  if (tid < 256) {
    int r2 = tid >> 7, x2 = tid & 127;
    float s = red[(0 * 2 + r2) * 128 + x2] + red[(1 * 2 + r2) * 128 + x2];
    float qq = red[512 + (0 * 2 + r2) * 128 + x2] +
               red[512 + (1 * 2 + r2) * 128 + x2];
    float m = s * (1.f / 128.f);
    float var = qq * (1.f / 128.f) - m * m;
    int q = b * HW_ + (y0 + r2) * 128 + x2;
    mu_o[q] = m;
    inv_o[q] = rsqrtf(var + 1e-5f);
  }
}

// ---- inhibited = relu(ff - relu((sig(alpha)*h_inh+mu)*LN(c1))) --------------
// ffio: IN = ff bf16 NCHW, OUT = inhibited bf16 NCHW (in-place).
// + bf16 channels-last copy + fused g2 LN stats
__global__ __launch_bounds__(256) void inhibit_k(
    const unsigned short* __restrict__ c1_raw_bf,
    unsigned short* __restrict__ ffio,
    const unsigned short* __restrict__ hinh_bf, const float* __restrict__ mu_s,
    const float* __restrict__ inv_s, const float* __restrict__ ps12,
    const float* __restrict__ pq12, const float* __restrict__ alpha,
    const float* __restrict__ mu_p, const float* __restrict__ gamma,
    const float* __restrict__ beta, unsigned short* __restrict__ out_cl,
    float* __restrict__ mu2_o, float* __restrict__ inv2_o) {
  __shared__ unsigned short tile[32 * 136];
  __shared__ float s8[8][32];
  __shared__ float q8[8][32];
  int blk = blockIdx.x;
  int b = blk >> 9;
  int p0 = (blk & 511) * 32;
  int t = threadIdx.x;
  int px = t & 31, cq = t >> 5;
  int q = b * HW_ + p0 + px;
  float muv = mu_s[q], invv = inv_s[q];
  size_t pixbase = (size_t)b * CHW_ + p0 + px;
  float sp = 0.f, qp = 0.f;
  for (int ci = 0; ci < 16; ++ci) {
    int c = cq * 16 + ci;
    size_t idx = pixbase + (size_t)c * HW_;
    float c1 = (bf2f(c1_raw_bf[idx]) - muv) * invv * gamma[c] + beta[c];
    float a = 1.f / (1.f + __expf(-alpha[c]));
    float r = fmaxf((a * bf2f(hinh_bf[idx]) + mu_p[c]) * c1, 0.f);
    float v = fmaxf(bf2f(ffio[idx]) - r, 0.f);
    unsigned short bv = f2bf(v);
    float vr = bf2f(bv);
    sp += vr;
    qp = fmaf(vr, vr, qp);
    ffio[idx] = bv;
    tile[px * 136 + c] = bv;
  }
  s8[cq][px] = sp;
  q8[cq][px] = qp;
  __syncthreads();
#pragma unroll
  for (int pass = 0; pass < 2; ++pass) {
    int u = pass * 256 + t;
    int ppx = u >> 4, cg = u & 15;
    u16x8 v = *(const u16x8*)(tile + ppx * 136 + cg * 8);
    *(u16x8*)(out_cl + (size_t)(b * HW_ + p0 + ppx) * 128 + cg * 8) = v;
  }
  if (t < 32) {
    float s = 0.f, qsum = 0.f;
#pragma unroll
    for (int k = 0; k < 8; ++k) {
      s += s8[k][t];
      qsum += q8[k][t];
    }
    int qn = b * HW_ + p0 + t;
    s += ps12[qn];
    qsum += pq12[qn];
    float m = s * (1.f / 384.f);
    float var = qsum * (1.f / 384.f) - m * m;
    mu2_o[qn] = m;
    inv2_o[qn] = rsqrtf(var + 1e-5f);
  }
}

extern "C" void kernel_launch(void* const* d_in, const int* in_sizes, int n_in,
                              void* d_out, int out_size, void* d_ws,
                              size_t ws_size, hipStream_t stream) {
  const float* ff     = (const float*)d_in[0];
  const float* h_exc  = (const float*)d_in[1];
  const float* h_inh  = (const float*)d_in[2];
  const float* W_gain = (const float*)d_in[3];
  const float* b_gain = (const float*)d_in[4];
  const float* W_mix  = (const float*)d_in[5];
  const float* b_mix  = (const float*)d_in[6];
  const float* W_inh  = (const float*)d_in[7];
  const float* W_exc  = (const float*)d_in[8];
  const float* alpha  = (const float*)d_in[9];
  const float* mu_p   = (const float*)d_in[10];
  const float* kappa  = (const float*)d_in[11];
  const float* omega  = (const float*)d_in[12];
  const float* c1_g   = (const float*)d_in[13];
  const float* c1_b   = (const float*)d_in[14];
  const float* c2_g   = (const float*)d_in[15];
  const float* c2_b   = (const float*)d_in[16];

  float* w = (float*)d_ws;
  unsigned short* Wp_inh = (unsigned short*)w;  w += 401408;
  unsigned short* Wp_exc = (unsigned short*)w;  w += 401408;
  unsigned short* Ag     = (unsigned short*)w;  w += 24576;
  unsigned short* Am     = (unsigned short*)w;  w += 24576;
  float* rs     = w;  w += 256;
  float* mu1    = w;  w += NPIX_;
  float* inv1   = w;  w += NPIX_;
  float* mu_c1  = w;  w += NPIX_;
  float* inv_c1 = w;  w += NPIX_;
  float* mu2    = w;  w += NPIX_;
  float* inv2   = w;  w += NPIX_;
  float* mu_c2  = w;  w += NPIX_;
  float* inv_c2 = w;  w += NPIX_;
  float* ps12   = w;  w += NPIX_;
  float* pq12   = w;  w += NPIX_;
  unsigned short* exc_bf   = (unsigned short*)w;  w += 8388608;
  unsigned short* hinh_bf  = (unsigned short*)w;  w += 8388608;
  unsigned short* ffinh_bf = (unsigned short*)w;  w += 8388608;  // ff, then inhibited
  unsigned short* conv_bf  = (unsigned short*)w;  w += 8388608;  // c1_raw, then c2_raw

  unsigned short* gated_cl = (unsigned short*)d_out;
  unsigned short* inh_cl   = (unsigned short*)d_out + (size_t)16777216;

  prep_w_bf16_k<<<3136, 256, 0, stream>>>(W_inh, W_exc, Wp_inh, Wp_exc);
  prep_apack_k<<<192, 256, 0, stream>>>(W_gain, W_mix, Ag, Am);
  rowsum_k<<<1, 256, 0, stream>>>(W_gain, W_mix, rs);

  // g1 LN stats + bf16 copies + (h_exc,h_inh) partial sums for g2
  stats3_cvt_k<<<512, 256, 0, stream>>>(h_exc, h_inh, ff, mu1, inv1, ps12,
                                        pq12, exc_bf, hinh_bf, ffinh_bf);
  // gated = h_exc * g1  (bf16 channels-last into d_out lo)
  {
    dim3 g(128, 8);
    gemm_mfma_k<0><<<g, 256, 0, stream>>>(
        Ag, rs, b_gain, exc_bf, hinh_bf, ffinh_bf, mu1, inv1, exc_bf, gated_cl,
        nullptr, nullptr, nullptr, nullptr, nullptr, nullptr, nullptr, nullptr,
        nullptr, nullptr);
  }
  // c1 = sym_conv(gated) + fused LN stats
  conv7_mfma_k<<<512, 512, 0, stream>>>(gated_cl, Wp_inh, conv_bf, mu_c1,
                                        inv_c1);
  // inhibited (in-place over ff bf16) + fused g2 LN stats
  inhibit_k<<<4096, 256, 0, stream>>>(conv_bf, ffinh_bf, hinh_bf, mu_c1,
                                      inv_c1, ps12, pq12, alpha, mu_p, c1_g,
                                      c1_b, inh_cl, mu2, inv2);
  // c2 = sym_conv(inhibited) + fused LN stats
  conv7_mfma_k<<<512, 512, 0, stream>>>(inh_cl, Wp_exc, conv_bf, mu_c2,
                                        inv_c2);
  // g2 gemm + fused final mix -> d_out f32 NCHW
  {
    dim3 g(128, 8);
    gemm_mfma_k<1><<<g, 256, 0, stream>>>(
        Am, rs + 128, b_mix, ffinh_bf, exc_bf, hinh_bf, mu2, inv2, nullptr,
        nullptr, conv_bf, mu_c2, inv_c2, ffinh_bf, exc_bf, c2_g, c2_b, kappa,
        omega, (float*)d_out);
  }
}

// Round 7
// 632.716 us; speedup vs baseline: 1.3579x; 1.3209x over previous
//
#include <hip/hip_runtime.h>
#include <cstddef>
#include <cstdint>

namespace {
constexpr int B_ = 8, C_ = 128, H_ = 128, W_ = 128;
constexpr int HW_ = H_ * W_;               // 16384
constexpr size_t CHW_ = (size_t)C_ * HW_;  // 2097152
constexpr int NPIX_ = B_ * HW_;            // 131072
}

typedef __attribute__((ext_vector_type(8))) short bf16x8;
typedef __attribute__((ext_vector_type(4))) float f32x4;
typedef __attribute__((ext_vector_type(8))) unsigned short u16x8;
typedef __attribute__((ext_vector_type(4))) unsigned short u16x4;

__device__ inline unsigned short f2bf(float f) {
  unsigned int u = __float_as_uint(f);
  unsigned int r = u + 0x7FFFu + ((u >> 16) & 1u);
  return (unsigned short)(r >> 16);
}
__device__ inline float bf2f(unsigned short u) {
  return __uint_as_float((unsigned int)u << 16);
}

// ---- conv weight prep: symmetrize, bf16, layout [tap49][grp16][oc128][ic8]
__global__ __launch_bounds__(256) void prep_w_bf16_k(
    const float* __restrict__ Wa, const float* __restrict__ Wb,
    unsigned short* __restrict__ Ta, unsigned short* __restrict__ Tb) {
  int idx = blockIdx.x * 256 + threadIdx.x;  // 802816
  int j = idx & 7;
  int o = (idx >> 3) & 127;
  int g = (idx >> 10) & 15;
  int t = idx >> 14;
  int i = g * 8 + j;
  int ky = t / 7, kx = t - ky * 7;
  size_t oi = ((size_t)(o * 128 + i) * 7 + ky) * 7 + kx;
  size_t io = ((size_t)(i * 128 + o) * 7 + ky) * 7 + kx;
  Ta[idx] = f2bf(0.5f * (Wa[oi] + Wa[io]));
  Tb[idx] = f2bf(0.5f * (Wb[oi] + Wb[io]));
}

// ---- 1x1 weight prep: bf16 fragment layout [s12][f8][lane64][j8] -----------
__global__ __launch_bounds__(256) void prep_apack_k(
    const float* __restrict__ Wg, const float* __restrict__ Wm,
    unsigned short* __restrict__ Ag, unsigned short* __restrict__ Am) {
  int idx = blockIdx.x * 256 + threadIdx.x;  // 49152
  int j = idx & 7;
  int l = (idx >> 3) & 63;
  int f = (idx >> 9) & 7;
  int s = idx >> 12;
  int m = f * 16 + (l & 15);
  int k = s * 32 + (l >> 4) * 8 + j;
  Ag[idx] = f2bf(Wg[m * 384 + k]);
  Am[idx] = f2bf(Wm[m * 384 + k]);
}

// ---- row sums of the 1x1 weights, on bf16-rounded values (LN folding) ------
__global__ void rowsum_k(const float* __restrict__ Wg,
                         const float* __restrict__ Wm, float* __restrict__ rs) {
  int t = threadIdx.x;
  const float* src = (t < 128) ? Wg : Wm;
  int row = t & 127;
  float s = 0.f;
  for (int i = 0; i < 384; ++i) s += bf2f(f2bf(src[row * 384 + i]));
  rs[t] = s;
}

// ---- LN stats over [h_exc,h_inh,ff] + CHANNELS-LAST bf16 copies + partial
// ---- sums over (h_exc,h_inh) for the later g2 LN ---------------------------
// Block: 256 thr, 32 pixels; LDS transpose tile per tensor.
__global__ __launch_bounds__(256) void stats3_cvt_k(
    const float* __restrict__ t0, const float* __restrict__ t1,
    const float* __restrict__ t2, float* __restrict__ mu_o,
    float* __restrict__ inv_o, float* __restrict__ ps12,
    float* __restrict__ pq12, unsigned short* __restrict__ o0,
    unsigned short* __restrict__ o1, unsigned short* __restrict__ o2) {
  __shared__ unsigned short tile[32 * 136];
  __shared__ float s8[8][32];
  __shared__ float q8[8][32];
  int blk = blockIdx.x;  // 4096 = 8 b x 512
  int b = blk >> 9;
  int p0 = (blk & 511) * 32;
  int t = threadIdx.x;
  int px = t & 31, cq = t >> 5;
  size_t base = (size_t)b * CHW_ + p0 + px;
  int pixg = b * HW_ + p0;
  float s = 0.f, s2 = 0.f;
  // tensor 0 (h_exc)
  for (int ci = 0; ci < 16; ++ci) {
    int c = cq * 16 + ci;
    float v = t0[base + (size_t)c * HW_];
    s += v; s2 = fmaf(v, v, s2);
    tile[px * 136 + c] = f2bf(v);
  }
  __syncthreads();
#pragma unroll
  for (int pass = 0; pass < 2; ++pass) {
    int u = pass * 256 + t;
    int ppx = u >> 4, cg = u & 15;
    *(u16x8*)(o0 + (size_t)(pixg + ppx) * 128 + cg * 8) =
        *(const u16x8*)(tile + ppx * 136 + cg * 8);
  }
  __syncthreads();
  // tensor 1 (h_inh)
  for (int ci = 0; ci < 16; ++ci) {
    int c = cq * 16 + ci;
    float v = t1[base + (size_t)c * HW_];
    s += v; s2 = fmaf(v, v, s2);
    tile[px * 136 + c] = f2bf(v);
  }
  s8[cq][px] = s;
  q8[cq][px] = s2;
  __syncthreads();
#pragma unroll
  for (int pass = 0; pass < 2; ++pass) {
    int u = pass * 256 + t;
    int ppx = u >> 4, cg = u & 15;
    *(u16x8*)(o1 + (size_t)(pixg + ppx) * 128 + cg * 8) =
        *(const u16x8*)(tile + ppx * 136 + cg * 8);
  }
  if (t < 32) {
    float ss = 0.f, qs = 0.f;
#pragma unroll
    for (int k = 0; k < 8; ++k) { ss += s8[k][t]; qs += q8[k][t]; }
    ps12[pixg + t] = ss;
    pq12[pixg + t] = qs;
  }
  __syncthreads();
  // tensor 2 (ff)
  for (int ci = 0; ci < 16; ++ci) {
    int c = cq * 16 + ci;
    float v = t2[base + (size_t)c * HW_];
    s += v; s2 = fmaf(v, v, s2);
    tile[px * 136 + c] = f2bf(v);
  }
  s8[cq][px] = s;
  q8[cq][px] = s2;
  __syncthreads();
#pragma unroll
  for (int pass = 0; pass < 2; ++pass) {
    int u = pass * 256 + t;
    int ppx = u >> 4, cg = u & 15;
    *(u16x8*)(o2 + (size_t)(pixg + ppx) * 128 + cg * 8) =
        *(const u16x8*)(tile + ppx * 136 + cg * 8);
  }
  if (t < 32) {
    float ss = 0.f, qs = 0.f;
#pragma unroll
    for (int k = 0; k < 8; ++k) { ss += s8[k][t]; qs += q8[k][t]; }
    float m = ss * (1.f / 384.f);
    float var = qs * (1.f / 384.f) - m * m;
    mu_o[pixg + t] = m;
    inv_o[pixg + t] = rsqrtf(var + 1e-5f);
  }
}

// ---- MFMA 1x1-conv gate GEMM, ALL-channels-last B operands -----------------
// FINAL=0: out_cl = bf16-cl gated = h_exc * sigmoid(LNfold)
// FINAL=1: out_f32 = f32 NCHW h_new = (1-g2)*h_exc + g2*h_tilde(c2, inh)
template <int FINAL>
__global__ __launch_bounds__(256) void gemm_mfma_k(
    const unsigned short* __restrict__ Apack, const float* __restrict__ rowsum,
    const float* __restrict__ bias, const unsigned short* __restrict__ B0,
    const unsigned short* __restrict__ B1, const unsigned short* __restrict__ B2,
    const float* __restrict__ mu, const float* __restrict__ inv,
    const unsigned short* __restrict__ mult_cl, unsigned short* __restrict__ out_cl,
    const unsigned short* __restrict__ c2_cl, const float* __restrict__ muc,
    const float* __restrict__ invc, const unsigned short* __restrict__ inh_cl,
    const unsigned short* __restrict__ hexc_cl, const float* __restrict__ c2g,
    const float* __restrict__ c2b, const float* __restrict__ kap,
    const float* __restrict__ omg, float* __restrict__ out_f32) {
  int b = blockIdx.y;
  int tid = threadIdx.x;
  int lane = tid & 63, wid = tid >> 6;
  int l15 = lane & 15, kg = lane >> 4;
  int n0 = blockIdx.x * 128 + wid * 32;
  int pix0 = b * HW_ + n0;
  size_t bofs = (size_t)b * CHW_;
  f32x4 acc[8][2] = {};
#pragma unroll
  for (int s = 0; s < 12; ++s) {
    const unsigned short* src = (s < 4) ? B0 : ((s < 8) ? B1 : B2);
    int ch0 = (s & 3) * 32 + kg * 8;
    bf16x8 bfr[2];
#pragma unroll
    for (int nf = 0; nf < 2; ++nf)
      bfr[nf] = *(const bf16x8*)(src + (size_t)(pix0 + nf * 16 + l15) * 128 + ch0);
    const bf16x8* ap = (const bf16x8*)(Apack + ((size_t)(s * 8) * 64 + lane) * 8);
#pragma unroll
    for (int f = 0; f < 8; ++f) {
      bf16x8 afr = ap[f * 64];
#pragma unroll
      for (int nf = 0; nf < 2; ++nf)
        acc[f][nf] = __builtin_amdgcn_mfma_f32_16x16x32_bf16(afr, bfr[nf],
                                                             acc[f][nf], 0, 0, 0);
    }
  }
#pragma unroll
  for (int nf = 0; nf < 2; ++nf) {
    int n = n0 + nf * 16 + l15;
    int qpix = b * HW_ + n;
    float muv = mu[qpix], invv = inv[qpix];
    if (!FINAL) {
#pragma unroll
      for (int mf = 0; mf < 8; ++mf) {
        int m0 = mf * 16 + kg * 4;
        f32x4 rs4 = *(const f32x4*)(rowsum + m0);
        f32x4 bi4 = *(const f32x4*)(bias + m0);
        u16x4 mv = *(const u16x4*)(mult_cl + (size_t)qpix * 128 + m0);
        u16x4 st;
#pragma unroll
        for (int j = 0; j < 4; ++j) {
          float val = invv * (acc[mf][nf][j] - muv * rs4[j]) + bi4[j];
          float g = 1.f / (1.f + __expf(-val));
          st[j] = f2bf(bf2f(mv[j]) * g);
        }
        *(u16x4*)(out_cl + (size_t)qpix * 128 + m0) = st;
      }
    } else {
      float mcv = muc[qpix], icv = invc[qpix];
#pragma unroll
      for (int mf = 0; mf < 8; ++mf) {
        int m0 = mf * 16 + kg * 4;
        f32x4 rs4 = *(const f32x4*)(rowsum + m0);
        f32x4 bi4 = *(const f32x4*)(bias + m0);
        f32x4 g4 = *(const f32x4*)(c2g + m0);
        f32x4 b4 = *(const f32x4*)(c2b + m0);
        f32x4 k4 = *(const f32x4*)(kap + m0);
        f32x4 o4 = *(const f32x4*)(omg + m0);
        u16x4 c2v = *(const u16x4*)(c2_cl + (size_t)qpix * 128 + m0);
        u16x4 iv4 = *(const u16x4*)(inh_cl + (size_t)qpix * 128 + m0);
        u16x4 hx4 = *(const u16x4*)(hexc_cl + (size_t)qpix * 128 + m0);
#pragma unroll
        for (int j = 0; j < 4; ++j) {
          float val = invv * (acc[mf][nf][j] - muv * rs4[j]) + bi4[j];
          float g2 = 1.f / (1.f + __expf(-val));
          float c2 = (bf2f(c2v[j]) - mcv) * icv * g4[j] + b4[j];
          float iv = bf2f(iv4[j]);
          float ht =
              fmaxf(k4[j] * (iv + c2) + fmaxf(o4[j], 0.f) * (iv * c2), 0.f);
          out_f32[bofs + (size_t)(m0 + j) * HW_ + n] =
              (1.f - g2) * bf2f(hx4[j]) + g2 * ht;
        }
      }
    }
  }
}

// ---- 7x7 SAME conv via MFMA bf16 (round-3 structure) + fused LN stats ------
// in_cl: [pix][128] bf16. Wp: [49][16][128][8] bf16. out: CHANNELS-LAST bf16.
// Block: 512 thr = 8 waves; tile 128oc x (2 rows x 128 px). Wave: 64oc x 64px.
__global__ __launch_bounds__(512, 4) void conv7_mfma_k(
    const unsigned short* __restrict__ in_cl,
    const unsigned short* __restrict__ Wp, unsigned short* __restrict__ out,
    float* __restrict__ mu_o, float* __restrict__ inv_o) {
  __shared__ short w_s[7 * 4 * 128 * 8];   // [kx][g][oc][8] 57344 B
  __shared__ short in_s[2 * 4 * 136 * 8];  // [r][g][xi][8]  17408 B
  int b = blockIdx.x >> 6;
  int y0 = (blockIdx.x & 63) * 2;
  int tid = threadIdx.x;
  int lane = tid & 63;
  int wid = tid >> 6;
  int wm = wid >> 2;  // 0..1 -> oc half
  int wn = wid & 3;   // 0..3 -> (row, px-half)
  int l15 = lane & 15, kg = lane >> 4;
  f32x4 acc[4][4] = {};
  for (int ky = 0; ky < 7; ++ky) {
    int ybase = y0 + ky - 3;
    for (int c4 = 0; c4 < 4; ++c4) {
      __syncthreads();
#pragma unroll
      for (int kx = 0; kx < 7; ++kx) {
        u16x8 wv = *(const u16x8*)(Wp + (size_t)(ky * 7 + kx) * 16384 +
                                   c4 * 4096 + tid * 8);
        *(u16x8*)(w_s + kx * 4096 + tid * 8) = wv;
      }
      for (int u = tid; u < 1088; u += 512) {
        int r = u / 544;
        int rem = u - r * 544;
        int g = rem / 136;
        int xi = rem - g * 136;
        int x = xi - 3;
        int y = ybase + r;
        u16x8 v = {};
        if (x >= 0 && x < 128 && y >= 0 && y < 128)
          v = *(const u16x8*)(in_cl + ((size_t)((b * 128 + y) * 128 + x) * 128 +
                                       c4 * 32 + g * 8));
        *(u16x8*)(in_s + u * 8) = v;
      }
      __syncthreads();
      for (int kx = 0; kx < 7; ++kx) {
        bf16x8 bfr[4], afr[4];
#pragma unroll
        for (int nf = 0; nf < 4; ++nf) {
          int xi = (wn & 1) * 64 + nf * 16 + l15 + kx;
          bfr[nf] = *(const bf16x8*)(in_s + (((wn >> 1) * 4 + kg) * 136 + xi) * 8);
        }
#pragma unroll
        for (int mf = 0; mf < 4; ++mf) {
          int oc = wm * 64 + mf * 16 + l15;
          afr[mf] = *(const bf16x8*)(w_s + ((kx * 4 + kg) * 128 + oc) * 8);
        }
#pragma unroll
        for (int mf = 0; mf < 4; ++mf)
#pragma unroll
          for (int nf = 0; nf < 4; ++nf)
            acc[mf][nf] = __builtin_amdgcn_mfma_f32_16x16x32_bf16(
                afr[mf], bfr[nf], acc[mf][nf], 0, 0, 0);
      }
    }
  }
  // ---- epilogue: bf16 channels-last store + fused per-pixel LN stats ----
  __syncthreads();  // compute done; in_s reusable as reduction scratch
  float* red = (float*)in_s;
  int row = wn >> 1;
  int y = y0 + row;
  int xb = (wn & 1) * 64;
#pragma unroll
  for (int nf = 0; nf < 4; ++nf) {
    int x = xb + nf * 16 + l15;
    size_t paddr = (size_t)(b * HW_ + y * 128 + x) * 128;
    float s = 0.f, qq = 0.f;
#pragma unroll
    for (int mf = 0; mf < 4; ++mf) {
      int oc0 = wm * 64 + mf * 16 + kg * 4;
      u16x4 st;
#pragma unroll
      for (int j = 0; j < 4; ++j) {
        unsigned short bv = f2bf(acc[mf][nf][j]);
        float vr = bf2f(bv);
        s += vr;
        qq = fmaf(vr, vr, qq);
        st[j] = bv;
      }
      *(u16x4*)(out + paddr + oc0) = st;
    }
    s += __shfl_xor(s, 16);
    qq += __shfl_xor(qq, 16);
    s += __shfl_xor(s, 32);
    qq += __shfl_xor(qq, 32);
    if (kg == 0) {
      red[(wm * 2 + row) * 128 + x] = s;
      red[512 + (wm * 2 + row) * 128 + x] = qq;
    }
  }
  __syncthreads();
  if (tid < 256) {
    int r2 = tid >> 7, x2 = tid & 127;
    float s = red[(0 * 2 + r2) * 128 + x2] + red[(1 * 2 + r2) * 128 + x2];
    float qq = red[512 + (0 * 2 + r2) * 128 + x2] +
               red[512 + (1 * 2 + r2) * 128 + x2];
    float m = s * (1.f / 128.f);
    float var = qq * (1.f / 128.f) - m * m;
    int q = b * HW_ + (y0 + r2) * 128 + x2;
    mu_o[q] = m;
    inv_o[q] = rsqrtf(var + 1e-5f);
  }
}

// ---- inhibited = relu(ff - relu((sig(alpha)*h_inh+mu)*LN(c1))) --------------
// All channels-last, fully coalesced; ffio_cl updated IN PLACE (ff -> inh).
// + fused g2 LN stats (own sums + precomputed h_exc/h_inh partials).
__global__ __launch_bounds__(256) void inhibit_k(
    const unsigned short* __restrict__ c1_cl,
    unsigned short* __restrict__ ffio_cl,
    const unsigned short* __restrict__ hinh_cl, const float* __restrict__ mu_s,
    const float* __restrict__ inv_s, const float* __restrict__ ps12,
    const float* __restrict__ pq12, const float* __restrict__ alpha,
    const float* __restrict__ mu_p, const float* __restrict__ gamma,
    const float* __restrict__ beta, float* __restrict__ mu2_o,
    float* __restrict__ inv2_o) {
  __shared__ float s16[16][17];
  __shared__ float q16[16][17];
  int blk = blockIdx.x;  // 8192 blocks x 16 px
  int t = threadIdx.x;
  int cg = t & 15, pxi = t >> 4;
  int pix = blk * 16 + pxi;
  size_t base = (size_t)pix * 128 + cg * 8;
  int c0 = cg * 8;
  float muv = mu_s[pix], invv = inv_s[pix];
  u16x8 c1v = *(const u16x8*)(c1_cl + base);
  u16x8 ffv = *(const u16x8*)(ffio_cl + base);
  u16x8 hiv = *(const u16x8*)(hinh_cl + base);
  f32x4 al0 = *(const f32x4*)(alpha + c0), al1 = *(const f32x4*)(alpha + c0 + 4);
  f32x4 mp0 = *(const f32x4*)(mu_p + c0), mp1 = *(const f32x4*)(mu_p + c0 + 4);
  f32x4 ga0 = *(const f32x4*)(gamma + c0), ga1 = *(const f32x4*)(gamma + c0 + 4);
  f32x4 be0 = *(const f32x4*)(beta + c0), be1 = *(const f32x4*)(beta + c0 + 4);
  float sp = 0.f, qp = 0.f;
  u16x8 ov;
#pragma unroll
  for (int j = 0; j < 8; ++j) {
    float alv = (j < 4) ? al0[j & 3] : al1[j & 3];
    float mpv = (j < 4) ? mp0[j & 3] : mp1[j & 3];
    float gav = (j < 4) ? ga0[j & 3] : ga1[j & 3];
    float bev = (j < 4) ? be0[j & 3] : be1[j & 3];
    float c1 = (bf2f(c1v[j]) - muv) * invv * gav + bev;
    float a = 1.f / (1.f + __expf(-alv));
    float r = fmaxf((a * bf2f(hiv[j]) + mpv) * c1, 0.f);
    float v = fmaxf(bf2f(ffv[j]) - r, 0.f);
    unsigned short bv = f2bf(v);
    float vr = bf2f(bv);
    sp += vr;
    qp = fmaf(vr, vr, qp);
    ov[j] = bv;
  }
  *(u16x8*)(ffio_cl + base) = ov;
  s16[pxi][cg] = sp;
  q16[pxi][cg] = qp;
  __syncthreads();
  if (t < 16) {
    float s = 0.f, qs = 0.f;
#pragma unroll
    for (int k = 0; k < 16; ++k) { s += s16[t][k]; qs += q16[t][k]; }
    int pg = blk * 16 + t;
    s += ps12[pg];
    qs += pq12[pg];
    float m = s * (1.f / 384.f);
    float var = qs * (1.f / 384.f) - m * m;
    mu2_o[pg] = m;
    inv2_o[pg] = rsqrtf(var + 1e-5f);
  }
}

extern "C" void kernel_launch(void* const* d_in, const int* in_sizes, int n_in,
                              void* d_out, int out_size, void* d_ws,
                              size_t ws_size, hipStream_t stream) {
  const float* ff     = (const float*)d_in[0];
  const float* h_exc  = (const float*)d_in[1];
  const float* h_inh  = (const float*)d_in[2];
  const float* W_gain = (const float*)d_in[3];
  const float* b_gain = (const float*)d_in[4];
  const float* W_mix  = (const float*)d_in[5];
  const float* b_mix  = (const float*)d_in[6];
  const float* W_inh  = (const float*)d_in[7];
  const float* W_exc  = (const float*)d_in[8];
  const float* alpha  = (const float*)d_in[9];
  const float* mu_p   = (const float*)d_in[10];
  const float* kappa  = (const float*)d_in[11];
  const float* omega  = (const float*)d_in[12];
  const float* c1_g   = (const float*)d_in[13];
  const float* c1_b   = (const float*)d_in[14];
  const float* c2_g   = (const float*)d_in[15];
  const float* c2_b   = (const float*)d_in[16];

  float* w = (float*)d_ws;
  unsigned short* Wp_inh = (unsigned short*)w;  w += 401408;
  unsigned short* Wp_exc = (unsigned short*)w;  w += 401408;
  unsigned short* Ag     = (unsigned short*)w;  w += 24576;
  unsigned short* Am     = (unsigned short*)w;  w += 24576;
  float* rs     = w;  w += 256;
  float* mu1    = w;  w += NPIX_;
  float* inv1   = w;  w += NPIX_;
  float* mu_c1  = w;  w += NPIX_;
  float* inv_c1 = w;  w += NPIX_;
  float* mu2    = w;  w += NPIX_;
  float* inv2   = w;  w += NPIX_;
  float* mu_c2  = w;  w += NPIX_;
  float* inv_c2 = w;  w += NPIX_;
  float* ps12   = w;  w += NPIX_;
  float* pq12   = w;  w += NPIX_;
  unsigned short* exc_cl   = (unsigned short*)w;  w += 8388608;
  unsigned short* hinh_cl  = (unsigned short*)w;  w += 8388608;
  unsigned short* ffinh_cl = (unsigned short*)w;  w += 8388608;  // ff -> inhibited
  unsigned short* conv_cl  = (unsigned short*)w;  w += 8388608;  // c1raw -> c2raw

  unsigned short* gated_cl = (unsigned short*)d_out;  // dead before final write

  prep_w_bf16_k<<<3136, 256, 0, stream>>>(W_inh, W_exc, Wp_inh, Wp_exc);
  prep_apack_k<<<192, 256, 0, stream>>>(W_gain, W_mix, Ag, Am);
  rowsum_k<<<1, 256, 0, stream>>>(W_gain, W_mix, rs);

  // g1 LN stats + channels-last bf16 copies + (h_exc,h_inh) partials for g2
  stats3_cvt_k<<<4096, 256, 0, stream>>>(h_exc, h_inh, ff, mu1, inv1, ps12,
                                         pq12, exc_cl, hinh_cl, ffinh_cl);
  // gated = h_exc * g1  (bf16 channels-last into d_out)
  {
    dim3 g(128, 8);
    gemm_mfma_k<0><<<g, 256, 0, stream>>>(
        Ag, rs, b_gain, exc_cl, hinh_cl, ffinh_cl, mu1, inv1, exc_cl, gated_cl,
        nullptr, nullptr, nullptr, nullptr, nullptr, nullptr, nullptr, nullptr,
        nullptr, nullptr);
  }
  // c1 = sym_conv(gated) + fused LN stats  (channels-last out)
  conv7_mfma_k<<<512, 512, 0, stream>>>(gated_cl, Wp_inh, conv_cl, mu_c1,
                                        inv_c1);
  // inhibited (in-place over ff_cl) + fused g2 LN stats
  inhibit_k<<<8192, 256, 0, stream>>>(conv_cl, ffinh_cl, hinh_cl, mu_c1,
                                      inv_c1, ps12, pq12, alpha, mu_p, c1_g,
                                      c1_b, mu2, inv2);
  // c2 = sym_conv(inhibited) + fused LN stats
  conv7_mfma_k<<<512, 512, 0, stream>>>(ffinh_cl, Wp_exc, conv_cl, mu_c2,
                                        inv_c2);
  // g2 gemm + fused final mix -> d_out f32 NCHW
  {
    dim3 g(128, 8);
    gemm_mfma_k<1><<<g, 256, 0, stream>>>(
        Am, rs + 128, b_mix, ffinh_cl, exc_cl, hinh_cl, mu2, inv2, nullptr,
        nullptr, conv_cl, mu_c2, inv_c2, ffinh_cl, exc_cl, c2_g, c2_b, kappa,
        omega, (float*)d_out);
  }
}

// Round 8
// 619.445 us; speedup vs baseline: 1.3870x; 1.0214x over previous
//
#include <hip/hip_runtime.h>
#include <cstddef>
#include <cstdint>

namespace {
constexpr int B_ = 8, C_ = 128, H_ = 128, W_ = 128;
constexpr int HW_ = H_ * W_;               // 16384
constexpr size_t CHW_ = (size_t)C_ * HW_;  // 2097152
constexpr int NPIX_ = B_ * HW_;            // 131072
}

typedef __attribute__((ext_vector_type(8))) short bf16x8;
typedef __attribute__((ext_vector_type(4))) float f32x4;
typedef __attribute__((ext_vector_type(8))) unsigned short u16x8;
typedef __attribute__((ext_vector_type(4))) unsigned short u16x4;

__device__ inline unsigned short f2bf(float f) {
  unsigned int u = __float_as_uint(f);
  unsigned int r = u + 0x7FFFu + ((u >> 16) & 1u);
  return (unsigned short)(r >> 16);
}
__device__ inline float bf2f(unsigned short u) {
  return __uint_as_float((unsigned int)u << 16);
}

// ---- conv weight prep: symmetrize, bf16, layout [tap49][grp16][oc128][ic8]
__global__ __launch_bounds__(256) void prep_w_bf16_k(
    const float* __restrict__ Wa, const float* __restrict__ Wb,
    unsigned short* __restrict__ Ta, unsigned short* __restrict__ Tb) {
  int idx = blockIdx.x * 256 + threadIdx.x;  // 802816
  int j = idx & 7;
  int o = (idx >> 3) & 127;
  int g = (idx >> 10) & 15;
  int t = idx >> 14;
  int i = g * 8 + j;
  int ky = t / 7, kx = t - ky * 7;
  size_t oi = ((size_t)(o * 128 + i) * 7 + ky) * 7 + kx;
  size_t io = ((size_t)(i * 128 + o) * 7 + ky) * 7 + kx;
  Ta[idx] = f2bf(0.5f * (Wa[oi] + Wa[io]));
  Tb[idx] = f2bf(0.5f * (Wb[oi] + Wb[io]));
}

// ---- 1x1 weight prep: bf16 fragment layout [s12][f8][lane64][j8] -----------
__global__ __launch_bounds__(256) void prep_apack_k(
    const float* __restrict__ Wg, const float* __restrict__ Wm,
    unsigned short* __restrict__ Ag, unsigned short* __restrict__ Am) {
  int idx = blockIdx.x * 256 + threadIdx.x;  // 49152
  int j = idx & 7;
  int l = (idx >> 3) & 63;
  int f = (idx >> 9) & 7;
  int s = idx >> 12;
  int m = f * 16 + (l & 15);
  int k = s * 32 + (l >> 4) * 8 + j;
  Ag[idx] = f2bf(Wg[m * 384 + k]);
  Am[idx] = f2bf(Wm[m * 384 + k]);
}

// ---- row sums of the 1x1 weights, on bf16-rounded values (LN folding) ------
__global__ void rowsum_k(const float* __restrict__ Wg,
                         const float* __restrict__ Wm, float* __restrict__ rs) {
  int t = threadIdx.x;
  const float* src = (t < 128) ? Wg : Wm;
  int row = t & 127;
  float s = 0.f;
  for (int i = 0; i < 384; ++i) s += bf2f(f2bf(src[row * 384 + i]));
  rs[t] = s;
}

// ---- LN stats over [h_exc,h_inh,ff] + CHANNELS-LAST bf16 copies + partial
// ---- sums over (h_exc,h_inh) for the later g2 LN ---------------------------
__global__ __launch_bounds__(256) void stats3_cvt_k(
    const float* __restrict__ t0, const float* __restrict__ t1,
    const float* __restrict__ t2, float* __restrict__ mu_o,
    float* __restrict__ inv_o, float* __restrict__ ps12,
    float* __restrict__ pq12, unsigned short* __restrict__ o0,
    unsigned short* __restrict__ o1, unsigned short* __restrict__ o2) {
  __shared__ unsigned short tile[32 * 136];
  __shared__ float s8[8][32];
  __shared__ float q8[8][32];
  int blk = blockIdx.x;  // 4096 = 8 b x 512
  int b = blk >> 9;
  int p0 = (blk & 511) * 32;
  int t = threadIdx.x;
  int px = t & 31, cq = t >> 5;
  size_t base = (size_t)b * CHW_ + p0 + px;
  int pixg = b * HW_ + p0;
  float s = 0.f, s2 = 0.f;
  for (int ci = 0; ci < 16; ++ci) {
    int c = cq * 16 + ci;
    float v = t0[base + (size_t)c * HW_];
    s += v; s2 = fmaf(v, v, s2);
    tile[px * 136 + c] = f2bf(v);
  }
  __syncthreads();
#pragma unroll
  for (int pass = 0; pass < 2; ++pass) {
    int u = pass * 256 + t;
    int ppx = u >> 4, cg = u & 15;
    *(u16x8*)(o0 + (size_t)(pixg + ppx) * 128 + cg * 8) =
        *(const u16x8*)(tile + ppx * 136 + cg * 8);
  }
  __syncthreads();
  for (int ci = 0; ci < 16; ++ci) {
    int c = cq * 16 + ci;
    float v = t1[base + (size_t)c * HW_];
    s += v; s2 = fmaf(v, v, s2);
    tile[px * 136 + c] = f2bf(v);
  }
  s8[cq][px] = s;
  q8[cq][px] = s2;
  __syncthreads();
#pragma unroll
  for (int pass = 0; pass < 2; ++pass) {
    int u = pass * 256 + t;
    int ppx = u >> 4, cg = u & 15;
    *(u16x8*)(o1 + (size_t)(pixg + ppx) * 128 + cg * 8) =
        *(const u16x8*)(tile + ppx * 136 + cg * 8);
  }
  if (t < 32) {
    float ss = 0.f, qs = 0.f;
#pragma unroll
    for (int k = 0; k < 8; ++k) { ss += s8[k][t]; qs += q8[k][t]; }
    ps12[pixg + t] = ss;
    pq12[pixg + t] = qs;
  }
  __syncthreads();
  for (int ci = 0; ci < 16; ++ci) {
    int c = cq * 16 + ci;
    float v = t2[base + (size_t)c * HW_];
    s += v; s2 = fmaf(v, v, s2);
    tile[px * 136 + c] = f2bf(v);
  }
  s8[cq][px] = s;
  q8[cq][px] = s2;
  __syncthreads();
#pragma unroll
  for (int pass = 0; pass < 2; ++pass) {
    int u = pass * 256 + t;
    int ppx = u >> 4, cg = u & 15;
    *(u16x8*)(o2 + (size_t)(pixg + ppx) * 128 + cg * 8) =
        *(const u16x8*)(tile + ppx * 136 + cg * 8);
  }
  if (t < 32) {
    float ss = 0.f, qs = 0.f;
#pragma unroll
    for (int k = 0; k < 8; ++k) { ss += s8[k][t]; qs += q8[k][t]; }
    float m = ss * (1.f / 384.f);
    float var = qs * (1.f / 384.f) - m * m;
    mu_o[pixg + t] = m;
    inv_o[pixg + t] = rsqrtf(var + 1e-5f);
  }
}

// ---- MFMA 1x1-conv gate GEMM, ALL-channels-last B operands -----------------
template <int FINAL>
__global__ __launch_bounds__(256) void gemm_mfma_k(
    const unsigned short* __restrict__ Apack, const float* __restrict__ rowsum,
    const float* __restrict__ bias, const unsigned short* __restrict__ B0,
    const unsigned short* __restrict__ B1, const unsigned short* __restrict__ B2,
    const float* __restrict__ mu, const float* __restrict__ inv,
    const unsigned short* __restrict__ mult_cl, unsigned short* __restrict__ out_cl,
    const unsigned short* __restrict__ c2_cl, const float* __restrict__ muc,
    const float* __restrict__ invc, const unsigned short* __restrict__ inh_cl,
    const unsigned short* __restrict__ hexc_cl, const float* __restrict__ c2g,
    const float* __restrict__ c2b, const float* __restrict__ kap,
    const float* __restrict__ omg, float* __restrict__ out_f32) {
  int b = blockIdx.y;
  int tid = threadIdx.x;
  int lane = tid & 63, wid = tid >> 6;
  int l15 = lane & 15, kg = lane >> 4;
  int n0 = blockIdx.x * 128 + wid * 32;
  int pix0 = b * HW_ + n0;
  size_t bofs = (size_t)b * CHW_;
  f32x4 acc[8][2] = {};
#pragma unroll
  for (int s = 0; s < 12; ++s) {
    const unsigned short* src = (s < 4) ? B0 : ((s < 8) ? B1 : B2);
    int ch0 = (s & 3) * 32 + kg * 8;
    bf16x8 bfr[2];
#pragma unroll
    for (int nf = 0; nf < 2; ++nf)
      bfr[nf] = *(const bf16x8*)(src + (size_t)(pix0 + nf * 16 + l15) * 128 + ch0);
    const bf16x8* ap = (const bf16x8*)(Apack + ((size_t)(s * 8) * 64 + lane) * 8);
#pragma unroll
    for (int f = 0; f < 8; ++f) {
      bf16x8 afr = ap[f * 64];
#pragma unroll
      for (int nf = 0; nf < 2; ++nf)
        acc[f][nf] = __builtin_amdgcn_mfma_f32_16x16x32_bf16(afr, bfr[nf],
                                                             acc[f][nf], 0, 0, 0);
    }
  }
#pragma unroll
  for (int nf = 0; nf < 2; ++nf) {
    int n = n0 + nf * 16 + l15;
    int qpix = b * HW_ + n;
    float muv = mu[qpix], invv = inv[qpix];
    if (!FINAL) {
#pragma unroll
      for (int mf = 0; mf < 8; ++mf) {
        int m0 = mf * 16 + kg * 4;
        f32x4 rs4 = *(const f32x4*)(rowsum + m0);
        f32x4 bi4 = *(const f32x4*)(bias + m0);
        u16x4 mv = *(const u16x4*)(mult_cl + (size_t)qpix * 128 + m0);
        u16x4 st;
#pragma unroll
        for (int j = 0; j < 4; ++j) {
          float val = invv * (acc[mf][nf][j] - muv * rs4[j]) + bi4[j];
          float g = 1.f / (1.f + __expf(-val));
          st[j] = f2bf(bf2f(mv[j]) * g);
        }
        *(u16x4*)(out_cl + (size_t)qpix * 128 + m0) = st;
      }
    } else {
      float mcv = muc[qpix], icv = invc[qpix];
#pragma unroll
      for (int mf = 0; mf < 8; ++mf) {
        int m0 = mf * 16 + kg * 4;
        f32x4 rs4 = *(const f32x4*)(rowsum + m0);
        f32x4 bi4 = *(const f32x4*)(bias + m0);
        f32x4 g4 = *(const f32x4*)(c2g + m0);
        f32x4 b4 = *(const f32x4*)(c2b + m0);
        f32x4 k4 = *(const f32x4*)(kap + m0);
        f32x4 o4 = *(const f32x4*)(omg + m0);
        u16x4 c2v = *(const u16x4*)(c2_cl + (size_t)qpix * 128 + m0);
        u16x4 iv4 = *(const u16x4*)(inh_cl + (size_t)qpix * 128 + m0);
        u16x4 hx4 = *(const u16x4*)(hexc_cl + (size_t)qpix * 128 + m0);
#pragma unroll
        for (int j = 0; j < 4; ++j) {
          float val = invv * (acc[mf][nf][j] - muv * rs4[j]) + bi4[j];
          float g2 = 1.f / (1.f + __expf(-val));
          float c2 = (bf2f(c2v[j]) - mcv) * icv * g4[j] + b4[j];
          float iv = bf2f(iv4[j]);
          float ht =
              fmaxf(k4[j] * (iv + c2) + fmaxf(o4[j], 0.f) * (iv * c2), 0.f);
          out_f32[bofs + (size_t)(m0 + j) * HW_ + n] =
              (1.f - g2) * bf2f(hx4[j]) + g2 * ht;
        }
      }
    }
  }
}

// ---- 7x7 SAME conv via MFMA bf16 + fused LN stats ---------------------------
// Wide-wave variant: block 256 thr = 4 waves; tile 128oc x (2 rows x 128 px).
// Wave (wm = oc-half, row): 64 oc x 128 px -> 12 ds_read_b128 per 32 MFMA.
// XCD swizzle: b = bid%8 (each XCD works one batch image; halo from L2).
__global__ __launch_bounds__(256, 2) void conv7_mfma_k(
    const unsigned short* __restrict__ in_cl,
    const unsigned short* __restrict__ Wp, unsigned short* __restrict__ out,
    float* __restrict__ mu_o, float* __restrict__ inv_o) {
  __shared__ short w_s[7 * 4 * 128 * 8];   // [kx][g][oc][8] 57344 B
  __shared__ short in_s[2 * 4 * 136 * 8];  // [r][g][xi][8]  17408 B
  int b = blockIdx.x & 7;                  // XCD-aware swizzle
  int y0 = ((blockIdx.x >> 3) & 63) * 2;
  int tid = threadIdx.x;
  int lane = tid & 63;
  int wid = tid >> 6;
  int wm = wid >> 1;   // oc half
  int row = wid & 1;   // output row
  int l15 = lane & 15, kg = lane >> 4;
  f32x4 acc[4][8] = {};
  for (int ky = 0; ky < 7; ++ky) {
    int ybase = y0 + ky - 3;
    for (int c4 = 0; c4 < 4; ++c4) {
      __syncthreads();
      // stage weights: 7 taps x 8KB
#pragma unroll
      for (int kx = 0; kx < 7; ++kx) {
#pragma unroll
        for (int h = 0; h < 2; ++h) {
          int u = h * 256 + tid;
          *(u16x8*)(w_s + kx * 4096 + u * 8) =
              *(const u16x8*)(Wp + (size_t)(ky * 7 + kx) * 16384 + c4 * 4096 +
                              u * 8);
        }
      }
      // stage input: 2 rows x 4 kgrp x 136 x (8 ic), zero-padded halo
      for (int u = tid; u < 1088; u += 256) {
        int r = u / 544;
        int rem = u - r * 544;
        int g = rem / 136;
        int xi = rem - g * 136;
        int x = xi - 3;
        int y = ybase + r;
        u16x8 v = {};
        if (x >= 0 && x < 128 && y >= 0 && y < 128)
          v = *(const u16x8*)(in_cl + ((size_t)((b * 128 + y) * 128 + x) * 128 +
                                       c4 * 32 + g * 8));
        *(u16x8*)(in_s + u * 8) = v;
      }
      __syncthreads();
      for (int kx = 0; kx < 7; ++kx) {
        bf16x8 bfr[8], afr[4];
#pragma unroll
        for (int nf = 0; nf < 8; ++nf) {
          int xi = nf * 16 + l15 + kx;
          bfr[nf] = *(const bf16x8*)(in_s + ((row * 4 + kg) * 136 + xi) * 8);
        }
#pragma unroll
        for (int mf = 0; mf < 4; ++mf) {
          int oc = wm * 64 + mf * 16 + l15;
          afr[mf] = *(const bf16x8*)(w_s + ((kx * 4 + kg) * 128 + oc) * 8);
        }
#pragma unroll
        for (int mf = 0; mf < 4; ++mf)
#pragma unroll
          for (int nf = 0; nf < 8; ++nf)
            acc[mf][nf] = __builtin_amdgcn_mfma_f32_16x16x32_bf16(
                afr[mf], bfr[nf], acc[mf][nf], 0, 0, 0);
      }
    }
  }
  // ---- epilogue: bf16 channels-last store + fused per-pixel LN stats ----
  __syncthreads();  // compute done; in_s reusable as reduction scratch
  float* red = (float*)in_s;
  int y = y0 + row;
#pragma unroll
  for (int nf = 0; nf < 8; ++nf) {
    int x = nf * 16 + l15;
    size_t paddr = (size_t)(b * HW_ + y * 128 + x) * 128;
    float s = 0.f, qq = 0.f;
#pragma unroll
    for (int mf = 0; mf < 4; ++mf) {
      int oc0 = wm * 64 + mf * 16 + kg * 4;
      u16x4 st;
#pragma unroll
      for (int j = 0; j < 4; ++j) {
        unsigned short bv = f2bf(acc[mf][nf][j]);
        float vr = bf2f(bv);
        s += vr;
        qq = fmaf(vr, vr, qq);
        st[j] = bv;
      }
      *(u16x4*)(out + paddr + oc0) = st;
    }
    s += __shfl_xor(s, 16);
    qq += __shfl_xor(qq, 16);
    s += __shfl_xor(s, 32);
    qq += __shfl_xor(qq, 32);
    if (kg == 0) {
      red[(wm * 2 + row) * 128 + x] = s;
      red[512 + (wm * 2 + row) * 128 + x] = qq;
    }
  }
  __syncthreads();
  {
    int r2 = tid >> 7, x2 = tid & 127;
    float s = red[(0 * 2 + r2) * 128 + x2] + red[(1 * 2 + r2) * 128 + x2];
    float qq = red[512 + (0 * 2 + r2) * 128 + x2] +
               red[512 + (1 * 2 + r2) * 128 + x2];
    float m = s * (1.f / 128.f);
    float var = qq * (1.f / 128.f) - m * m;
    int q = b * HW_ + (y0 + r2) * 128 + x2;
    mu_o[q] = m;
    inv_o[q] = rsqrtf(var + 1e-5f);
  }
}

// ---- inhibited = relu(ff - relu((sig(alpha)*h_inh+mu)*LN(c1))) --------------
// All channels-last, fully coalesced; ffio_cl updated IN PLACE (ff -> inh).
__global__ __launch_bounds__(256) void inhibit_k(
    const unsigned short* __restrict__ c1_cl,
    unsigned short* __restrict__ ffio_cl,
    const unsigned short* __restrict__ hinh_cl, const float* __restrict__ mu_s,
    const float* __restrict__ inv_s, const float* __restrict__ ps12,
    const float* __restrict__ pq12, const float* __restrict__ alpha,
    const float* __restrict__ mu_p, const float* __restrict__ gamma,
    const float* __restrict__ beta, float* __restrict__ mu2_o,
    float* __restrict__ inv2_o) {
  __shared__ float s16[16][17];
  __shared__ float q16[16][17];
  int blk = blockIdx.x;  // 8192 blocks x 16 px
  int t = threadIdx.x;
  int cg = t & 15, pxi = t >> 4;
  int pix = blk * 16 + pxi;
  size_t base = (size_t)pix * 128 + cg * 8;
  int c0 = cg * 8;
  float muv = mu_s[pix], invv = inv_s[pix];
  u16x8 c1v = *(const u16x8*)(c1_cl + base);
  u16x8 ffv = *(const u16x8*)(ffio_cl + base);
  u16x8 hiv = *(const u16x8*)(hinh_cl + base);
  f32x4 al0 = *(const f32x4*)(alpha + c0), al1 = *(const f32x4*)(alpha + c0 + 4);
  f32x4 mp0 = *(const f32x4*)(mu_p + c0), mp1 = *(const f32x4*)(mu_p + c0 + 4);
  f32x4 ga0 = *(const f32x4*)(gamma + c0), ga1 = *(const f32x4*)(gamma + c0 + 4);
  f32x4 be0 = *(const f32x4*)(beta + c0), be1 = *(const f32x4*)(beta + c0 + 4);
  float sp = 0.f, qp = 0.f;
  u16x8 ov;
#pragma unroll
  for (int j = 0; j < 8; ++j) {
    float alv = (j < 4) ? al0[j & 3] : al1[j & 3];
    float mpv = (j < 4) ? mp0[j & 3] : mp1[j & 3];
    float gav = (j < 4) ? ga0[j & 3] : ga1[j & 3];
    float bev = (j < 4) ? be0[j & 3] : be1[j & 3];
    float c1 = (bf2f(c1v[j]) - muv) * invv * gav + bev;
    float a = 1.f / (1.f + __expf(-alv));
    float r = fmaxf((a * bf2f(hiv[j]) + mpv) * c1, 0.f);
    float v = fmaxf(bf2f(ffv[j]) - r, 0.f);
    unsigned short bv = f2bf(v);
    float vr = bf2f(bv);
    sp += vr;
    qp = fmaf(vr, vr, qp);
    ov[j] = bv;
  }
  *(u16x8*)(ffio_cl + base) = ov;
  s16[pxi][cg] = sp;
  q16[pxi][cg] = qp;
  __syncthreads();
  if (t < 16) {
    float s = 0.f, qs = 0.f;
#pragma unroll
    for (int k = 0; k < 16; ++k) { s += s16[t][k]; qs += q16[t][k]; }
    int pg = blk * 16 + t;
    s += ps12[pg];
    qs += pq12[pg];
    float m = s * (1.f / 384.f);
    float var = qs * (1.f / 384.f) - m * m;
    mu2_o[pg] = m;
    inv2_o[pg] = rsqrtf(var + 1e-5f);
  }
}

extern "C" void kernel_launch(void* const* d_in, const int* in_sizes, int n_in,
                              void* d_out, int out_size, void* d_ws,
                              size_t ws_size, hipStream_t stream) {
  const float* ff     = (const float*)d_in[0];
  const float* h_exc  = (const float*)d_in[1];
  const float* h_inh  = (const float*)d_in[2];
  const float* W_gain = (const float*)d_in[3];
  const float* b_gain = (const float*)d_in[4];
  const float* W_mix  = (const float*)d_in[5];
  const float* b_mix  = (const float*)d_in[6];
  const float* W_inh  = (const float*)d_in[7];
  const float* W_exc  = (const float*)d_in[8];
  const float* alpha  = (const float*)d_in[9];
  const float* mu_p   = (const float*)d_in[10];
  const float* kappa  = (const float*)d_in[11];
  const float* omega  = (const float*)d_in[12];
  const float* c1_g   = (const float*)d_in[13];
  const float* c1_b   = (const float*)d_in[14];
  const float* c2_g   = (const float*)d_in[15];
  const float* c2_b   = (const float*)d_in[16];

  float* w = (float*)d_ws;
  unsigned short* Wp_inh = (unsigned short*)w;  w += 401408;
  unsigned short* Wp_exc = (unsigned short*)w;  w += 401408;
  unsigned short* Ag     = (unsigned short*)w;  w += 24576;
  unsigned short* Am     = (unsigned short*)w;  w += 24576;
  float* rs     = w;  w += 256;
  float* mu1    = w;  w += NPIX_;
  float* inv1   = w;  w += NPIX_;
  float* mu_c1  = w;  w += NPIX_;
  float* inv_c1 = w;  w += NPIX_;
  float* mu2    = w;  w += NPIX_;
  float* inv2   = w;  w += NPIX_;
  float* mu_c2  = w;  w += NPIX_;
  float* inv_c2 = w;  w += NPIX_;
  float* ps12   = w;  w += NPIX_;
  float* pq12   = w;  w += NPIX_;
  unsigned short* exc_cl   = (unsigned short*)w;  w += 8388608;
  unsigned short* hinh_cl  = (unsigned short*)w;  w += 8388608;
  unsigned short* ffinh_cl = (unsigned short*)w;  w += 8388608;  // ff -> inhibited
  unsigned short* conv_cl  = (unsigned short*)w;  w += 8388608;  // c1raw -> c2raw

  unsigned short* gated_cl = (unsigned short*)d_out;  // dead before final write

  prep_w_bf16_k<<<3136, 256, 0, stream>>>(W_inh, W_exc, Wp_inh, Wp_exc);
  prep_apack_k<<<192, 256, 0, stream>>>(W_gain, W_mix, Ag, Am);
  rowsum_k<<<1, 256, 0, stream>>>(W_gain, W_mix, rs);

  // g1 LN stats + channels-last bf16 copies + (h_exc,h_inh) partials for g2
  stats3_cvt_k<<<4096, 256, 0, stream>>>(h_exc, h_inh, ff, mu1, inv1, ps12,
                                         pq12, exc_cl, hinh_cl, ffinh_cl);
  // gated = h_exc * g1  (bf16 channels-last into d_out)
  {
    dim3 g(128, 8);
    gemm_mfma_k<0><<<g, 256, 0, stream>>>(
        Ag, rs, b_gain, exc_cl, hinh_cl, ffinh_cl, mu1, inv1, exc_cl, gated_cl,
        nullptr, nullptr, nullptr, nullptr, nullptr, nullptr, nullptr, nullptr,
        nullptr, nullptr);
  }
  // c1 = sym_conv(gated) + fused LN stats  (channels-last out)
  conv7_mfma_k<<<512, 256, 0, stream>>>(gated_cl, Wp_inh, conv_cl, mu_c1,
                                        inv_c1);
  // inhibited (in-place over ff_cl) + fused g2 LN stats
  inhibit_k<<<8192, 256, 0, stream>>>(conv_cl, ffinh_cl, hinh_cl, mu_c1,
                                      inv_c1, ps12, pq12, alpha, mu_p, c1_g,
                                      c1_b, mu2, inv2);
  // c2 = sym_conv(inhibited) + fused LN stats
  conv7_mfma_k<<<512, 256, 0, stream>>>(ffinh_cl, Wp_exc, conv_cl, mu_c2,
                                        inv_c2);
  // g2 gemm + fused final mix -> d_out f32 NCHW
  {
    dim3 g(128, 8);
    gemm_mfma_k<1><<<g, 256, 0, stream>>>(
        Am, rs + 128, b_mix, ffinh_cl, exc_cl, hinh_cl, mu2, inv2, nullptr,
        nullptr, conv_cl, mu_c2, inv_c2, ffinh_cl, exc_cl, c2_g, c2_b, kappa,
        omega, (float*)d_out);
  }
}

// Round 9
// 603.543 us; speedup vs baseline: 1.4235x; 1.0263x over previous
//
#include <hip/hip_runtime.h>
#include <cstddef>
#include <cstdint>

namespace {
constexpr int B_ = 8, C_ = 128, H_ = 128, W_ = 128;
constexpr int HW_ = H_ * W_;               // 16384
constexpr size_t CHW_ = (size_t)C_ * HW_;  // 2097152
constexpr int NPIX_ = B_ * HW_;            // 131072
}

typedef __attribute__((ext_vector_type(8))) short bf16x8;
typedef __attribute__((ext_vector_type(4))) float f32x4;
typedef __attribute__((ext_vector_type(8))) unsigned short u16x8;
typedef __attribute__((ext_vector_type(4))) unsigned short u16x4;

__device__ inline unsigned short f2bf(float f) {
  unsigned int u = __float_as_uint(f);
  unsigned int r = u + 0x7FFFu + ((u >> 16) & 1u);
  return (unsigned short)(r >> 16);
}
__device__ inline float bf2f(unsigned short u) {
  return __uint_as_float((unsigned int)u << 16);
}

// async 16B global->LDS DMA (wave-uniform LDS base + lane*16 semantics)
__device__ inline void async_copy16(void* lds_dst, const void* gsrc) {
  __builtin_amdgcn_global_load_lds(
      (const __attribute__((address_space(1))) unsigned int*)gsrc,
      (__attribute__((address_space(3))) unsigned int*)lds_dst, 16, 0, 0);
}

// ---- conv weight prep: symmetrize, bf16, layout [tap49][grp16][oc128][ic8]
__global__ __launch_bounds__(256) void prep_w_bf16_k(
    const float* __restrict__ Wa, const float* __restrict__ Wb,
    unsigned short* __restrict__ Ta, unsigned short* __restrict__ Tb) {
  int idx = blockIdx.x * 256 + threadIdx.x;  // 802816
  int j = idx & 7;
  int o = (idx >> 3) & 127;
  int g = (idx >> 10) & 15;
  int t = idx >> 14;
  int i = g * 8 + j;
  int ky = t / 7, kx = t - ky * 7;
  size_t oi = ((size_t)(o * 128 + i) * 7 + ky) * 7 + kx;
  size_t io = ((size_t)(i * 128 + o) * 7 + ky) * 7 + kx;
  Ta[idx] = f2bf(0.5f * (Wa[oi] + Wa[io]));
  Tb[idx] = f2bf(0.5f * (Wb[oi] + Wb[io]));
}

// ---- 1x1 weight prep: bf16 fragment layout [s12][f8][lane64][j8] -----------
__global__ __launch_bounds__(256) void prep_apack_k(
    const float* __restrict__ Wg, const float* __restrict__ Wm,
    unsigned short* __restrict__ Ag, unsigned short* __restrict__ Am) {
  int idx = blockIdx.x * 256 + threadIdx.x;  // 49152
  int j = idx & 7;
  int l = (idx >> 3) & 63;
  int f = (idx >> 9) & 7;
  int s = idx >> 12;
  int m = f * 16 + (l & 15);
  int k = s * 32 + (l >> 4) * 8 + j;
  Ag[idx] = f2bf(Wg[m * 384 + k]);
  Am[idx] = f2bf(Wm[m * 384 + k]);
}

// ---- row sums of the 1x1 weights, on bf16-rounded values (LN folding) ------
__global__ void rowsum_k(const float* __restrict__ Wg,
                         const float* __restrict__ Wm, float* __restrict__ rs) {
  int t = threadIdx.x;
  const float* src = (t < 128) ? Wg : Wm;
  int row = t & 127;
  float s = 0.f;
  for (int i = 0; i < 384; ++i) s += bf2f(f2bf(src[row * 384 + i]));
  rs[t] = s;
}

// ---- LN stats over [h_exc,h_inh,ff] + CHANNELS-LAST bf16 copies + partial
// ---- sums over (h_exc,h_inh) for the later g2 LN ---------------------------
__global__ __launch_bounds__(256) void stats3_cvt_k(
    const float* __restrict__ t0, const float* __restrict__ t1,
    const float* __restrict__ t2, float* __restrict__ mu_o,
    float* __restrict__ inv_o, float* __restrict__ ps12,
    float* __restrict__ pq12, unsigned short* __restrict__ o0,
    unsigned short* __restrict__ o1, unsigned short* __restrict__ o2) {
  __shared__ unsigned short tile[32 * 136];
  __shared__ float s8[8][32];
  __shared__ float q8[8][32];
  int blk = blockIdx.x;  // 4096 = 8 b x 512
  int b = blk >> 9;
  int p0 = (blk & 511) * 32;
  int t = threadIdx.x;
  int px = t & 31, cq = t >> 5;
  size_t base = (size_t)b * CHW_ + p0 + px;
  int pixg = b * HW_ + p0;
  float s = 0.f, s2 = 0.f;
  for (int ci = 0; ci < 16; ++ci) {
    int c = cq * 16 + ci;
    float v = t0[base + (size_t)c * HW_];
    s += v; s2 = fmaf(v, v, s2);
    tile[px * 136 + c] = f2bf(v);
  }
  __syncthreads();
#pragma unroll
  for (int pass = 0; pass < 2; ++pass) {
    int u = pass * 256 + t;
    int ppx = u >> 4, cg = u & 15;
    *(u16x8*)(o0 + (size_t)(pixg + ppx) * 128 + cg * 8) =
        *(const u16x8*)(tile + ppx * 136 + cg * 8);
  }
  __syncthreads();
  for (int ci = 0; ci < 16; ++ci) {
    int c = cq * 16 + ci;
    float v = t1[base + (size_t)c * HW_];
    s += v; s2 = fmaf(v, v, s2);
    tile[px * 136 + c] = f2bf(v);
  }
  s8[cq][px] = s;
  q8[cq][px] = s2;
  __syncthreads();
#pragma unroll
  for (int pass = 0; pass < 2; ++pass) {
    int u = pass * 256 + t;
    int ppx = u >> 4, cg = u & 15;
    *(u16x8*)(o1 + (size_t)(pixg + ppx) * 128 + cg * 8) =
        *(const u16x8*)(tile + ppx * 136 + cg * 8);
  }
  if (t < 32) {
    float ss = 0.f, qs = 0.f;
#pragma unroll
    for (int k = 0; k < 8; ++k) { ss += s8[k][t]; qs += q8[k][t]; }
    ps12[pixg + t] = ss;
    pq12[pixg + t] = qs;
  }
  __syncthreads();
  for (int ci = 0; ci < 16; ++ci) {
    int c = cq * 16 + ci;
    float v = t2[base + (size_t)c * HW_];
    s += v; s2 = fmaf(v, v, s2);
    tile[px * 136 + c] = f2bf(v);
  }
  s8[cq][px] = s;
  q8[cq][px] = s2;
  __syncthreads();
#pragma unroll
  for (int pass = 0; pass < 2; ++pass) {
    int u = pass * 256 + t;
    int ppx = u >> 4, cg = u & 15;
    *(u16x8*)(o2 + (size_t)(pixg + ppx) * 128 + cg * 8) =
        *(const u16x8*)(tile + ppx * 136 + cg * 8);
  }
  if (t < 32) {
    float ss = 0.f, qs = 0.f;
#pragma unroll
    for (int k = 0; k < 8; ++k) { ss += s8[k][t]; qs += q8[k][t]; }
    float m = ss * (1.f / 384.f);
    float var = qs * (1.f / 384.f) - m * m;
    mu_o[pixg + t] = m;
    inv_o[pixg + t] = rsqrtf(var + 1e-5f);
  }
}

// ---- MFMA 1x1-conv gate GEMM, ALL-channels-last B operands -----------------
template <int FINAL>
__global__ __launch_bounds__(256) void gemm_mfma_k(
    const unsigned short* __restrict__ Apack, const float* __restrict__ rowsum,
    const float* __restrict__ bias, const unsigned short* __restrict__ B0,
    const unsigned short* __restrict__ B1, const unsigned short* __restrict__ B2,
    const float* __restrict__ mu, const float* __restrict__ inv,
    const unsigned short* __restrict__ mult_cl, unsigned short* __restrict__ out_cl,
    const unsigned short* __restrict__ c2_cl, const float* __restrict__ muc,
    const float* __restrict__ invc, const unsigned short* __restrict__ inh_cl,
    const unsigned short* __restrict__ hexc_cl, const float* __restrict__ c2g,
    const float* __restrict__ c2b, const float* __restrict__ kap,
    const float* __restrict__ omg, float* __restrict__ out_f32) {
  int b = blockIdx.y;
  int tid = threadIdx.x;
  int lane = tid & 63, wid = tid >> 6;
  int l15 = lane & 15, kg = lane >> 4;
  int n0 = blockIdx.x * 128 + wid * 32;
  int pix0 = b * HW_ + n0;
  size_t bofs = (size_t)b * CHW_;
  f32x4 acc[8][2] = {};
#pragma unroll
  for (int s = 0; s < 12; ++s) {
    const unsigned short* src = (s < 4) ? B0 : ((s < 8) ? B1 : B2);
    int ch0 = (s & 3) * 32 + kg * 8;
    bf16x8 bfr[2];
#pragma unroll
    for (int nf = 0; nf < 2; ++nf)
      bfr[nf] = *(const bf16x8*)(src + (size_t)(pix0 + nf * 16 + l15) * 128 + ch0);
    const bf16x8* ap = (const bf16x8*)(Apack + ((size_t)(s * 8) * 64 + lane) * 8);
#pragma unroll
    for (int f = 0; f < 8; ++f) {
      bf16x8 afr = ap[f * 64];
#pragma unroll
      for (int nf = 0; nf < 2; ++nf)
        acc[f][nf] = __builtin_amdgcn_mfma_f32_16x16x32_bf16(afr, bfr[nf],
                                                             acc[f][nf], 0, 0, 0);
    }
  }
#pragma unroll
  for (int nf = 0; nf < 2; ++nf) {
    int n = n0 + nf * 16 + l15;
    int qpix = b * HW_ + n;
    float muv = mu[qpix], invv = inv[qpix];
    if (!FINAL) {
#pragma unroll
      for (int mf = 0; mf < 8; ++mf) {
        int m0 = mf * 16 + kg * 4;
        f32x4 rs4 = *(const f32x4*)(rowsum + m0);
        f32x4 bi4 = *(const f32x4*)(bias + m0);
        u16x4 mv = *(const u16x4*)(mult_cl + (size_t)qpix * 128 + m0);
        u16x4 st;
#pragma unroll
        for (int j = 0; j < 4; ++j) {
          float val = invv * (acc[mf][nf][j] - muv * rs4[j]) + bi4[j];
          float g = 1.f / (1.f + __expf(-val));
          st[j] = f2bf(bf2f(mv[j]) * g);
        }
        *(u16x4*)(out_cl + (size_t)qpix * 128 + m0) = st;
      }
    } else {
      float mcv = muc[qpix], icv = invc[qpix];
#pragma unroll
      for (int mf = 0; mf < 8; ++mf) {
        int m0 = mf * 16 + kg * 4;
        f32x4 rs4 = *(const f32x4*)(rowsum + m0);
        f32x4 bi4 = *(const f32x4*)(bias + m0);
        f32x4 g4 = *(const f32x4*)(c2g + m0);
        f32x4 b4 = *(const f32x4*)(c2b + m0);
        f32x4 k4 = *(const f32x4*)(kap + m0);
        f32x4 o4 = *(const f32x4*)(omg + m0);
        u16x4 c2v = *(const u16x4*)(c2_cl + (size_t)qpix * 128 + m0);
        u16x4 iv4 = *(const u16x4*)(inh_cl + (size_t)qpix * 128 + m0);
        u16x4 hx4 = *(const u16x4*)(hexc_cl + (size_t)qpix * 128 + m0);
#pragma unroll
        for (int j = 0; j < 4; ++j) {
          float val = invv * (acc[mf][nf][j] - muv * rs4[j]) + bi4[j];
          float g2 = 1.f / (1.f + __expf(-val));
          float c2 = (bf2f(c2v[j]) - mcv) * icv * g4[j] + b4[j];
          float iv = bf2f(iv4[j]);
          float ht =
              fmaxf(k4[j] * (iv + c2) + fmaxf(o4[j], 0.f) * (iv * c2), 0.f);
          out_f32[bofs + (size_t)(m0 + j) * HW_ + n] =
              (1.f - g2) * bf2f(hx4[j]) + g2 * ht;
        }
      }
    }
  }
}

// ---- 7x7 SAME conv via MFMA bf16 + fused LN stats ---------------------------
// Wide-wave: block 256 thr = 4 waves; tile 128oc x (2 rows x 128 px).
// Weights staged via async global_load_lds DMA (16B/lane, linear layout).
// XCD swizzle: b = bid%8.
__global__ __launch_bounds__(256, 2) void conv7_mfma_k(
    const unsigned short* __restrict__ in_cl,
    const unsigned short* __restrict__ Wp, unsigned short* __restrict__ out,
    float* __restrict__ mu_o, float* __restrict__ inv_o) {
  __shared__ short w_s[7 * 4 * 128 * 8];   // [kx][g][oc][8] 57344 B
  __shared__ short in_s[2 * 4 * 136 * 8];  // [r][g][xi][8]  17408 B
  int b = blockIdx.x & 7;                  // XCD-aware swizzle
  int y0 = ((blockIdx.x >> 3) & 63) * 2;
  int tid = threadIdx.x;
  int lane = tid & 63;
  int wid = tid >> 6;
  int wm = wid >> 1;   // oc half
  int row = wid & 1;   // output row
  int l15 = lane & 15, kg = lane >> 4;
  f32x4 acc[4][8] = {};
  for (int ky = 0; ky < 7; ++ky) {
    int ybase = y0 + ky - 3;
    for (int c4 = 0; c4 < 4; ++c4) {
      __syncthreads();
      // weights: async DMA, 7 taps x 8KB, issued first so input staging
      // latency overlaps the DMA
      const unsigned short* wsrc =
          Wp + (size_t)(ky * 7) * 16384 + c4 * 4096 + tid * 8;
#pragma unroll
      for (int kx = 0; kx < 7; ++kx) {
#pragma unroll
        for (int h = 0; h < 2; ++h) {
          async_copy16(w_s + kx * 4096 + (h * 256 + tid) * 8,
                       wsrc + kx * 16384 + h * 2048);
        }
      }
      // input: 2 rows x 4 kgrp x 136 x (8 ic), zero-padded halo (register path)
      for (int u = tid; u < 1088; u += 256) {
        int r = u / 544;
        int rem = u - r * 544;
        int g = rem / 136;
        int xi = rem - g * 136;
        int x = xi - 3;
        int y = ybase + r;
        u16x8 v = {};
        if (x >= 0 && x < 128 && y >= 0 && y < 128)
          v = *(const u16x8*)(in_cl + ((size_t)((b * 128 + y) * 128 + x) * 128 +
                                       c4 * 32 + g * 8));
        *(u16x8*)(in_s + u * 8) = v;
      }
      __syncthreads();
      for (int kx = 0; kx < 7; ++kx) {
        bf16x8 bfr[8], afr[4];
#pragma unroll
        for (int nf = 0; nf < 8; ++nf) {
          int xi = nf * 16 + l15 + kx;
          bfr[nf] = *(const bf16x8*)(in_s + ((row * 4 + kg) * 136 + xi) * 8);
        }
#pragma unroll
        for (int mf = 0; mf < 4; ++mf) {
          int oc = wm * 64 + mf * 16 + l15;
          afr[mf] = *(const bf16x8*)(w_s + ((kx * 4 + kg) * 128 + oc) * 8);
        }
#pragma unroll
        for (int mf = 0; mf < 4; ++mf)
#pragma unroll
          for (int nf = 0; nf < 8; ++nf)
            acc[mf][nf] = __builtin_amdgcn_mfma_f32_16x16x32_bf16(
                afr[mf], bfr[nf], acc[mf][nf], 0, 0, 0);
      }
    }
  }
  // ---- epilogue: bf16 channels-last store + fused per-pixel LN stats ----
  __syncthreads();  // compute done; in_s reusable as reduction scratch
  float* red = (float*)in_s;
  int y = y0 + row;
#pragma unroll
  for (int nf = 0; nf < 8; ++nf) {
    int x = nf * 16 + l15;
    size_t paddr = (size_t)(b * HW_ + y * 128 + x) * 128;
    float s = 0.f, qq = 0.f;
#pragma unroll
    for (int mf = 0; mf < 4; ++mf) {
      int oc0 = wm * 64 + mf * 16 + kg * 4;
      u16x4 st;
#pragma unroll
      for (int j = 0; j < 4; ++j) {
        unsigned short bv = f2bf(acc[mf][nf][j]);
        float vr = bf2f(bv);
        s += vr;
        qq = fmaf(vr, vr, qq);
        st[j] = bv;
      }
      *(u16x4*)(out + paddr + oc0) = st;
    }
    s += __shfl_xor(s, 16);
    qq += __shfl_xor(qq, 16);
    s += __shfl_xor(s, 32);
    qq += __shfl_xor(qq, 32);
    if (kg == 0) {
      red[(wm * 2 + row) * 128 + x] = s;
      red[512 + (wm * 2 + row) * 128 + x] = qq;
    }
  }
  __syncthreads();
  {
    int r2 = tid >> 7, x2 = tid & 127;
    float s = red[(0 * 2 + r2) * 128 + x2] + red[(1 * 2 + r2) * 128 + x2];
    float qq = red[512 + (0 * 2 + r2) * 128 + x2] +
               red[512 + (1 * 2 + r2) * 128 + x2];
    float m = s * (1.f / 128.f);
    float var = qq * (1.f / 128.f) - m * m;
    int q = b * HW_ + (y0 + r2) * 128 + x2;
    mu_o[q] = m;
    inv_o[q] = rsqrtf(var + 1e-5f);
  }
}

// ---- inhibited = relu(ff - relu((sig(alpha)*h_inh+mu)*LN(c1))) --------------
// All channels-last, fully coalesced; ffio_cl updated IN PLACE (ff -> inh).
__global__ __launch_bounds__(256) void inhibit_k(
    const unsigned short* __restrict__ c1_cl,
    unsigned short* __restrict__ ffio_cl,
    const unsigned short* __restrict__ hinh_cl, const float* __restrict__ mu_s,
    const float* __restrict__ inv_s, const float* __restrict__ ps12,
    const float* __restrict__ pq12, const float* __restrict__ alpha,
    const float* __restrict__ mu_p, const float* __restrict__ gamma,
    const float* __restrict__ beta, float* __restrict__ mu2_o,
    float* __restrict__ inv2_o) {
  __shared__ float s16[16][17];
  __shared__ float q16[16][17];
  int blk = blockIdx.x;  // 8192 blocks x 16 px
  int t = threadIdx.x;
  int cg = t & 15, pxi = t >> 4;
  int pix = blk * 16 + pxi;
  size_t base = (size_t)pix * 128 + cg * 8;
  int c0 = cg * 8;
  float muv = mu_s[pix], invv = inv_s[pix];
  u16x8 c1v = *(const u16x8*)(c1_cl + base);
  u16x8 ffv = *(const u16x8*)(ffio_cl + base);
  u16x8 hiv = *(const u16x8*)(hinh_cl + base);
  f32x4 al0 = *(const f32x4*)(alpha + c0), al1 = *(const f32x4*)(alpha + c0 + 4);
  f32x4 mp0 = *(const f32x4*)(mu_p + c0), mp1 = *(const f32x4*)(mu_p + c0 + 4);
  f32x4 ga0 = *(const f32x4*)(gamma + c0), ga1 = *(const f32x4*)(gamma + c0 + 4);
  f32x4 be0 = *(const f32x4*)(beta + c0), be1 = *(const f32x4*)(beta + c0 + 4);
  float sp = 0.f, qp = 0.f;
  u16x8 ov;
#pragma unroll
  for (int j = 0; j < 8; ++j) {
    float alv = (j < 4) ? al0[j & 3] : al1[j & 3];
    float mpv = (j < 4) ? mp0[j & 3] : mp1[j & 3];
    float gav = (j < 4) ? ga0[j & 3] : ga1[j & 3];
    float bev = (j < 4) ? be0[j & 3] : be1[j & 3];
    float c1 = (bf2f(c1v[j]) - muv) * invv * gav + bev;
    float a = 1.f / (1.f + __expf(-alv));
    float r = fmaxf((a * bf2f(hiv[j]) + mpv) * c1, 0.f);
    float v = fmaxf(bf2f(ffv[j]) - r, 0.f);
    unsigned short bv = f2bf(v);
    float vr = bf2f(bv);
    sp += vr;
    qp = fmaf(vr, vr, qp);
    ov[j] = bv;
  }
  *(u16x8*)(ffio_cl + base) = ov;
  s16[pxi][cg] = sp;
  q16[pxi][cg] = qp;
  __syncthreads();
  if (t < 16) {
    float s = 0.f, qs = 0.f;
#pragma unroll
    for (int k = 0; k < 16; ++k) { s += s16[t][k]; qs += q16[t][k]; }
    int pg = blk * 16 + t;
    s += ps12[pg];
    qs += pq12[pg];
    float m = s * (1.f / 384.f);
    float var = qs * (1.f / 384.f) - m * m;
    mu2_o[pg] = m;
    inv2_o[pg] = rsqrtf(var + 1e-5f);
  }
}

extern "C" void kernel_launch(void* const* d_in, const int* in_sizes, int n_in,
                              void* d_out, int out_size, void* d_ws,
                              size_t ws_size, hipStream_t stream) {
  const float* ff     = (const float*)d_in[0];
  const float* h_exc  = (const float*)d_in[1];
  const float* h_inh  = (const float*)d_in[2];
  const float* W_gain = (const float*)d_in[3];
  const float* b_gain = (const float*)d_in[4];
  const float* W_mix  = (const float*)d_in[5];
  const float* b_mix  = (const float*)d_in[6];
  const float* W_inh  = (const float*)d_in[7];
  const float* W_exc  = (const float*)d_in[8];
  const float* alpha  = (const float*)d_in[9];
  const float* mu_p   = (const float*)d_in[10];
  const float* kappa  = (const float*)d_in[11];
  const float* omega  = (const float*)d_in[12];
  const float* c1_g   = (const float*)d_in[13];
  const float* c1_b   = (const float*)d_in[14];
  const float* c2_g   = (const float*)d_in[15];
  const float* c2_b   = (const float*)d_in[16];

  float* w = (float*)d_ws;
  unsigned short* Wp_inh = (unsigned short*)w;  w += 401408;
  unsigned short* Wp_exc = (unsigned short*)w;  w += 401408;
  unsigned short* Ag     = (unsigned short*)w;  w += 24576;
  unsigned short* Am     = (unsigned short*)w;  w += 24576;
  float* rs     = w;  w += 256;
  float* mu1    = w;  w += NPIX_;
  float* inv1   = w;  w += NPIX_;
  float* mu_c1  = w;  w += NPIX_;
  float* inv_c1 = w;  w += NPIX_;
  float* mu2    = w;  w += NPIX_;
  float* inv2   = w;  w += NPIX_;
  float* mu_c2  = w;  w += NPIX_;
  float* inv_c2 = w;  w += NPIX_;
  float* ps12   = w;  w += NPIX_;
  float* pq12   = w;  w += NPIX_;
  unsigned short* exc_cl   = (unsigned short*)w;  w += 8388608;
  unsigned short* hinh_cl  = (unsigned short*)w;  w += 8388608;
  unsigned short* ffinh_cl = (unsigned short*)w;  w += 8388608;  // ff -> inhibited
  unsigned short* conv_cl  = (unsigned short*)w;  w += 8388608;  // c1raw -> c2raw

  unsigned short* gated_cl = (unsigned short*)d_out;  // dead before final write

  prep_w_bf16_k<<<3136, 256, 0, stream>>>(W_inh, W_exc, Wp_inh, Wp_exc);
  prep_apack_k<<<192, 256, 0, stream>>>(W_gain, W_mix, Ag, Am);
  rowsum_k<<<1, 256, 0, stream>>>(W_gain, W_mix, rs);

  // g1 LN stats + channels-last bf16 copies + (h_exc,h_inh) partials for g2
  stats3_cvt_k<<<4096, 256, 0, stream>>>(h_exc, h_inh, ff, mu1, inv1, ps12,
                                         pq12, exc_cl, hinh_cl, ffinh_cl);
  // gated = h_exc * g1  (bf16 channels-last into d_out)
  {
    dim3 g(128, 8);
    gemm_mfma_k<0><<<g, 256, 0, stream>>>(
        Ag, rs, b_gain, exc_cl, hinh_cl, ffinh_cl, mu1, inv1, exc_cl, gated_cl,
        nullptr, nullptr, nullptr, nullptr, nullptr, nullptr, nullptr, nullptr,
        nullptr, nullptr);
  }
  // c1 = sym_conv(gated) + fused LN stats  (channels-last out)
  conv7_mfma_k<<<512, 256, 0, stream>>>(gated_cl, Wp_inh, conv_cl, mu_c1,
                                        inv_c1);
  // inhibited (in-place over ff_cl) + fused g2 LN stats
  inhibit_k<<<8192, 256, 0, stream>>>(conv_cl, ffinh_cl, hinh_cl, mu_c1,
                                      inv_c1, ps12, pq12, alpha, mu_p, c1_g,
                                      c1_b, mu2, inv2);
  // c2 = sym_conv(inhibited) + fused LN stats
  conv7_mfma_k<<<512, 256, 0, stream>>>(ffinh_cl, Wp_exc, conv_cl, mu_c2,
                                        inv_c2);
  // g2 gemm + fused final mix -> d_out f32 NCHW
  {
    dim3 g(128, 8);
    gemm_mfma_k<1><<<g, 256, 0, stream>>>(
        Am, rs + 128, b_mix, ffinh_cl, exc_cl, hinh_cl, mu2, inv2, nullptr,
        nullptr, conv_cl, mu_c2, inv_c2, ffinh_cl, exc_cl, c2_g, c2_b, kappa,
        omega, (float*)d_out);
  }
}

// Round 10
// 594.077 us; speedup vs baseline: 1.4462x; 1.0159x over previous
//
#include <hip/hip_runtime.h>
#include <cstddef>
#include <cstdint>

namespace {
constexpr int B_ = 8, C_ = 128, H_ = 128, W_ = 128;
constexpr int HW_ = H_ * W_;               // 16384
constexpr size_t CHW_ = (size_t)C_ * HW_;  // 2097152
constexpr int NPIX_ = B_ * HW_;            // 131072
}

typedef __attribute__((ext_vector_type(8))) short bf16x8;
typedef __attribute__((ext_vector_type(4))) float f32x4;
typedef __attribute__((ext_vector_type(8))) unsigned short u16x8;
typedef __attribute__((ext_vector_type(4))) unsigned short u16x4;

__device__ inline unsigned short f2bf(float f) {
  unsigned int u = __float_as_uint(f);
  unsigned int r = u + 0x7FFFu + ((u >> 16) & 1u);
  return (unsigned short)(r >> 16);
}
__device__ inline float bf2f(unsigned short u) {
  return __uint_as_float((unsigned int)u << 16);
}

// async 16B global->LDS DMA (wave-uniform LDS base + lane*16 semantics)
__device__ inline void async_copy16(void* lds_dst, const void* gsrc) {
  __builtin_amdgcn_global_load_lds(
      (const __attribute__((address_space(1))) unsigned int*)gsrc,
      (__attribute__((address_space(3))) unsigned int*)lds_dst, 16, 0, 0);
}

// ---- conv weight prep: symmetrize, bf16, layout [tap49][grp16][oc128][ic8]
__global__ __launch_bounds__(256) void prep_w_bf16_k(
    const float* __restrict__ Wa, const float* __restrict__ Wb,
    unsigned short* __restrict__ Ta, unsigned short* __restrict__ Tb) {
  int idx = blockIdx.x * 256 + threadIdx.x;  // 802816
  int j = idx & 7;
  int o = (idx >> 3) & 127;
  int g = (idx >> 10) & 15;
  int t = idx >> 14;
  int i = g * 8 + j;
  int ky = t / 7, kx = t - ky * 7;
  size_t oi = ((size_t)(o * 128 + i) * 7 + ky) * 7 + kx;
  size_t io = ((size_t)(i * 128 + o) * 7 + ky) * 7 + kx;
  Ta[idx] = f2bf(0.5f * (Wa[oi] + Wa[io]));
  Tb[idx] = f2bf(0.5f * (Wb[oi] + Wb[io]));
}

// ---- 1x1 weight prep: bf16 fragment layout [s12][f8][lane64][j8] -----------
__global__ __launch_bounds__(256) void prep_apack_k(
    const float* __restrict__ Wg, const float* __restrict__ Wm,
    unsigned short* __restrict__ Ag, unsigned short* __restrict__ Am) {
  int idx = blockIdx.x * 256 + threadIdx.x;  // 49152
  int j = idx & 7;
  int l = (idx >> 3) & 63;
  int f = (idx >> 9) & 7;
  int s = idx >> 12;
  int m = f * 16 + (l & 15);
  int k = s * 32 + (l >> 4) * 8 + j;
  Ag[idx] = f2bf(Wg[m * 384 + k]);
  Am[idx] = f2bf(Wm[m * 384 + k]);
}

// ---- row sums of the 1x1 weights (LN folding) + sigmoid(alpha) table -------
__global__ void rowsum_k(const float* __restrict__ Wg,
                         const float* __restrict__ Wm,
                         const float* __restrict__ alpha,
                         float* __restrict__ rs, float* __restrict__ sa) {
  int t = threadIdx.x;
  const float* src = (t < 128) ? Wg : Wm;
  int row = t & 127;
  float s = 0.f;
  for (int i = 0; i < 384; ++i) s += bf2f(f2bf(src[row * 384 + i]));
  rs[t] = s;
  if (t < 128) sa[t] = 1.f / (1.f + __expf(-alpha[t]));
}

// ---- LN stats over [h_exc,h_inh,ff] + CHANNELS-LAST bf16 copies + partial
// ---- sums over (h_exc,h_inh) for the later g2 LN ---------------------------
__global__ __launch_bounds__(256) void stats3_cvt_k(
    const float* __restrict__ t0, const float* __restrict__ t1,
    const float* __restrict__ t2, float* __restrict__ mu_o,
    float* __restrict__ inv_o, float* __restrict__ ps12,
    float* __restrict__ pq12, unsigned short* __restrict__ o0,
    unsigned short* __restrict__ o1, unsigned short* __restrict__ o2) {
  __shared__ unsigned short tile[32 * 136];
  __shared__ float s8[8][32];
  __shared__ float q8[8][32];
  int blk = blockIdx.x;  // 4096 = 8 b x 512
  int b = blk >> 9;
  int p0 = (blk & 511) * 32;
  int t = threadIdx.x;
  int px = t & 31, cq = t >> 5;
  size_t base = (size_t)b * CHW_ + p0 + px;
  int pixg = b * HW_ + p0;
  float s = 0.f, s2 = 0.f;
  for (int ci = 0; ci < 16; ++ci) {
    int c = cq * 16 + ci;
    float v = t0[base + (size_t)c * HW_];
    s += v; s2 = fmaf(v, v, s2);
    tile[px * 136 + c] = f2bf(v);
  }
  __syncthreads();
#pragma unroll
  for (int pass = 0; pass < 2; ++pass) {
    int u = pass * 256 + t;
    int ppx = u >> 4, cg = u & 15;
    *(u16x8*)(o0 + (size_t)(pixg + ppx) * 128 + cg * 8) =
        *(const u16x8*)(tile + ppx * 136 + cg * 8);
  }
  __syncthreads();
  for (int ci = 0; ci < 16; ++ci) {
    int c = cq * 16 + ci;
    float v = t1[base + (size_t)c * HW_];
    s += v; s2 = fmaf(v, v, s2);
    tile[px * 136 + c] = f2bf(v);
  }
  s8[cq][px] = s;
  q8[cq][px] = s2;
  __syncthreads();
#pragma unroll
  for (int pass = 0; pass < 2; ++pass) {
    int u = pass * 256 + t;
    int ppx = u >> 4, cg = u & 15;
    *(u16x8*)(o1 + (size_t)(pixg + ppx) * 128 + cg * 8) =
        *(const u16x8*)(tile + ppx * 136 + cg * 8);
  }
  if (t < 32) {
    float ss = 0.f, qs = 0.f;
#pragma unroll
    for (int k = 0; k < 8; ++k) { ss += s8[k][t]; qs += q8[k][t]; }
    ps12[pixg + t] = ss;
    pq12[pixg + t] = qs;
  }
  __syncthreads();
  for (int ci = 0; ci < 16; ++ci) {
    int c = cq * 16 + ci;
    float v = t2[base + (size_t)c * HW_];
    s += v; s2 = fmaf(v, v, s2);
    tile[px * 136 + c] = f2bf(v);
  }
  s8[cq][px] = s;
  q8[cq][px] = s2;
  __syncthreads();
#pragma unroll
  for (int pass = 0; pass < 2; ++pass) {
    int u = pass * 256 + t;
    int ppx = u >> 4, cg = u & 15;
    *(u16x8*)(o2 + (size_t)(pixg + ppx) * 128 + cg * 8) =
        *(const u16x8*)(tile + ppx * 136 + cg * 8);
  }
  if (t < 32) {
    float ss = 0.f, qs = 0.f;
#pragma unroll
    for (int k = 0; k < 8; ++k) { ss += s8[k][t]; qs += q8[k][t]; }
    float m = ss * (1.f / 384.f);
    float var = qs * (1.f / 384.f) - m * m;
    mu_o[pixg + t] = m;
    inv_o[pixg + t] = rsqrtf(var + 1e-5f);
  }
}

// ---- MFMA 1x1-conv gate GEMM, ALL-channels-last B operands -----------------
template <int FINAL>
__global__ __launch_bounds__(256) void gemm_mfma_k(
    const unsigned short* __restrict__ Apack, const float* __restrict__ rowsum,
    const float* __restrict__ bias, const unsigned short* __restrict__ B0,
    const unsigned short* __restrict__ B1, const unsigned short* __restrict__ B2,
    const float* __restrict__ mu, const float* __restrict__ inv,
    const unsigned short* __restrict__ mult_cl, unsigned short* __restrict__ out_cl,
    const unsigned short* __restrict__ c2_cl, const float* __restrict__ muc,
    const float* __restrict__ invc, const unsigned short* __restrict__ inh_cl,
    const unsigned short* __restrict__ hexc_cl, const float* __restrict__ c2g,
    const float* __restrict__ c2b, const float* __restrict__ kap,
    const float* __restrict__ omg, float* __restrict__ out_f32) {
  int b = blockIdx.y;
  int tid = threadIdx.x;
  int lane = tid & 63, wid = tid >> 6;
  int l15 = lane & 15, kg = lane >> 4;
  int n0 = blockIdx.x * 128 + wid * 32;
  int pix0 = b * HW_ + n0;
  size_t bofs = (size_t)b * CHW_;
  f32x4 acc[8][2] = {};
#pragma unroll
  for (int s = 0; s < 12; ++s) {
    const unsigned short* src = (s < 4) ? B0 : ((s < 8) ? B1 : B2);
    int ch0 = (s & 3) * 32 + kg * 8;
    bf16x8 bfr[2];
#pragma unroll
    for (int nf = 0; nf < 2; ++nf)
      bfr[nf] = *(const bf16x8*)(src + (size_t)(pix0 + nf * 16 + l15) * 128 + ch0);
    const bf16x8* ap = (const bf16x8*)(Apack + ((size_t)(s * 8) * 64 + lane) * 8);
#pragma unroll
    for (int f = 0; f < 8; ++f) {
      bf16x8 afr = ap[f * 64];
#pragma unroll
      for (int nf = 0; nf < 2; ++nf)
        acc[f][nf] = __builtin_amdgcn_mfma_f32_16x16x32_bf16(afr, bfr[nf],
                                                             acc[f][nf], 0, 0, 0);
    }
  }
#pragma unroll
  for (int nf = 0; nf < 2; ++nf) {
    int n = n0 + nf * 16 + l15;
    int qpix = b * HW_ + n;
    float muv = mu[qpix], invv = inv[qpix];
    if (!FINAL) {
#pragma unroll
      for (int mf = 0; mf < 8; ++mf) {
        int m0 = mf * 16 + kg * 4;
        f32x4 rs4 = *(const f32x4*)(rowsum + m0);
        f32x4 bi4 = *(const f32x4*)(bias + m0);
        u16x4 mv = *(const u16x4*)(mult_cl + (size_t)qpix * 128 + m0);
        u16x4 st;
#pragma unroll
        for (int j = 0; j < 4; ++j) {
          float val = invv * (acc[mf][nf][j] - muv * rs4[j]) + bi4[j];
          float g = 1.f / (1.f + __expf(-val));
          st[j] = f2bf(bf2f(mv[j]) * g);
        }
        *(u16x4*)(out_cl + (size_t)qpix * 128 + m0) = st;
      }
    } else {
      float mcv = muc[qpix], icv = invc[qpix];
#pragma unroll
      for (int mf = 0; mf < 8; ++mf) {
        int m0 = mf * 16 + kg * 4;
        f32x4 rs4 = *(const f32x4*)(rowsum + m0);
        f32x4 bi4 = *(const f32x4*)(bias + m0);
        f32x4 g4 = *(const f32x4*)(c2g + m0);
        f32x4 b4 = *(const f32x4*)(c2b + m0);
        f32x4 k4 = *(const f32x4*)(kap + m0);
        f32x4 o4 = *(const f32x4*)(omg + m0);
        u16x4 c2v = *(const u16x4*)(c2_cl + (size_t)qpix * 128 + m0);
        u16x4 iv4 = *(const u16x4*)(inh_cl + (size_t)qpix * 128 + m0);
        u16x4 hx4 = *(const u16x4*)(hexc_cl + (size_t)qpix * 128 + m0);
#pragma unroll
        for (int j = 0; j < 4; ++j) {
          float val = invv * (acc[mf][nf][j] - muv * rs4[j]) + bi4[j];
          float g2 = 1.f / (1.f + __expf(-val));
          float c2 = (bf2f(c2v[j]) - mcv) * icv * g4[j] + b4[j];
          float iv = bf2f(iv4[j]);
          float ht =
              fmaxf(k4[j] * (iv + c2) + fmaxf(o4[j], 0.f) * (iv * c2), 0.f);
          out_f32[bofs + (size_t)(m0 + j) * HW_ + n] =
              (1.f - g2) * bf2f(hx4[j]) + g2 * ht;
        }
      }
    }
  }
}

// ---- 7x7 SAME conv via MFMA bf16 + fused LN stats ---------------------------
// Wide-wave: block 256 thr = 4 waves; tile 128oc x (2 rows x 128 px).
// Weights via async global_load_lds DMA. XCD swizzle b = bid%8.
// FUSE_INH=1: epilogue applies LN(c1)+inhibit in-register, writes INHIBITED
//   channels-last (in-place over ff_cl) and emits g2 LN stats (mu2/inv2,
//   using ps12/pq12 partials). c1_raw never touches memory.
// FUSE_INH=0: plain epilogue (store conv result cl + own LN stats).
template <int FUSE_INH>
__global__ __launch_bounds__(256, 2) void conv7_mfma_k(
    const unsigned short* __restrict__ in_cl,
    const unsigned short* __restrict__ Wp, unsigned short* out,
    float* __restrict__ mu_o, float* __restrict__ inv_o,
    const unsigned short* ff_cl, const unsigned short* __restrict__ hinh_cl,
    const float* __restrict__ ps12, const float* __restrict__ pq12,
    const float* __restrict__ sig_alpha, const float* __restrict__ mu_p,
    const float* __restrict__ gamma, const float* __restrict__ beta) {
  __shared__ short w_s[7 * 4 * 128 * 8];   // [kx][g][oc][8] 57344 B
  __shared__ short in_s[2 * 4 * 136 * 8];  // [r][g][xi][8]  17408 B
  int b = blockIdx.x & 7;                  // XCD-aware swizzle
  int y0 = ((blockIdx.x >> 3) & 63) * 2;
  int tid = threadIdx.x;
  int lane = tid & 63;
  int wid = tid >> 6;
  int wm = wid >> 1;   // oc half
  int row = wid & 1;   // output row
  int l15 = lane & 15, kg = lane >> 4;
  f32x4 acc[4][8] = {};
  for (int ky = 0; ky < 7; ++ky) {
    int ybase = y0 + ky - 3;
    for (int c4 = 0; c4 < 4; ++c4) {
      __syncthreads();
      // weights: async DMA, 7 taps x 8KB, issued first
      const unsigned short* wsrc =
          Wp + (size_t)(ky * 7) * 16384 + c4 * 4096 + tid * 8;
#pragma unroll
      for (int kx = 0; kx < 7; ++kx) {
#pragma unroll
        for (int h = 0; h < 2; ++h) {
          async_copy16(w_s + kx * 4096 + (h * 256 + tid) * 8,
                       wsrc + kx * 16384 + h * 2048);
        }
      }
      // input: 2 rows x 4 kgrp x 136 x (8 ic), zero-padded halo
      for (int u = tid; u < 1088; u += 256) {
        int r = u / 544;
        int rem = u - r * 544;
        int g = rem / 136;
        int xi = rem - g * 136;
        int x = xi - 3;
        int y = ybase + r;
        u16x8 v = {};
        if (x >= 0 && x < 128 && y >= 0 && y < 128)
          v = *(const u16x8*)(in_cl + ((size_t)((b * 128 + y) * 128 + x) * 128 +
                                       c4 * 32 + g * 8));
        *(u16x8*)(in_s + u * 8) = v;
      }
      __syncthreads();
      for (int kx = 0; kx < 7; ++kx) {
        bf16x8 bfr[8], afr[4];
#pragma unroll
        for (int nf = 0; nf < 8; ++nf) {
          int xi = nf * 16 + l15 + kx;
          bfr[nf] = *(const bf16x8*)(in_s + ((row * 4 + kg) * 136 + xi) * 8);
        }
#pragma unroll
        for (int mf = 0; mf < 4; ++mf) {
          int oc = wm * 64 + mf * 16 + l15;
          afr[mf] = *(const bf16x8*)(w_s + ((kx * 4 + kg) * 128 + oc) * 8);
        }
#pragma unroll
        for (int mf = 0; mf < 4; ++mf)
#pragma unroll
          for (int nf = 0; nf < 8; ++nf)
            acc[mf][nf] = __builtin_amdgcn_mfma_f32_16x16x32_bf16(
                afr[mf], bfr[nf], acc[mf][nf], 0, 0, 0);
      }
    }
  }
  // ---- epilogue ----
  __syncthreads();  // compute done; in_s reusable as reduction scratch
  float* red = (float*)in_s;  // [0..511]=s, [512..1023]=q, [1024..1535]=mu/inv
  int y = y0 + row;
  // phase A: LN stats of bf16-rounded conv result (+ store if !FUSE_INH)
#pragma unroll
  for (int nf = 0; nf < 8; ++nf) {
    int x = nf * 16 + l15;
    size_t paddr = (size_t)(b * HW_ + y * 128 + x) * 128;
    float s = 0.f, qq = 0.f;
#pragma unroll
    for (int mf = 0; mf < 4; ++mf) {
      int oc0 = wm * 64 + mf * 16 + kg * 4;
      u16x4 st;
#pragma unroll
      for (int j = 0; j < 4; ++j) {
        unsigned short bv = f2bf(acc[mf][nf][j]);
        float vr = bf2f(bv);
        s += vr;
        qq = fmaf(vr, vr, qq);
        st[j] = bv;
      }
      if (!FUSE_INH) *(u16x4*)(out + paddr + oc0) = st;
    }
    s += __shfl_xor(s, 16);
    qq += __shfl_xor(qq, 16);
    s += __shfl_xor(s, 32);
    qq += __shfl_xor(qq, 32);
    if (kg == 0) {
      red[(wm * 2 + row) * 128 + x] = s;
      red[512 + (wm * 2 + row) * 128 + x] = qq;
    }
  }
  __syncthreads();
  // phase B: finalize per-pixel LN stats
  {
    int r2 = tid >> 7, x2 = tid & 127;
    float s = red[r2 * 128 + x2] + red[(2 + r2) * 128 + x2];
    float qq = red[512 + r2 * 128 + x2] + red[512 + (2 + r2) * 128 + x2];
    float m = s * (1.f / 128.f);
    float var = qq * (1.f / 128.f) - m * m;
    float ivv = rsqrtf(var + 1e-5f);
    if (FUSE_INH) {
      red[1024 + r2 * 128 + x2] = m;
      red[1280 + r2 * 128 + x2] = ivv;
    } else {
      int q = b * HW_ + (y0 + r2) * 128 + x2;
      mu_o[q] = m;
      inv_o[q] = ivv;
    }
  }
  if (!FUSE_INH) return;
  __syncthreads();
  // phase C: apply LN + inhibit in-register, write inhibited, sum for g2 LN
  f32x4 ga4[4], be4[4], sa4[4], mp4[4];
#pragma unroll
  for (int mf = 0; mf < 4; ++mf) {
    int oc0 = wm * 64 + mf * 16 + kg * 4;
    ga4[mf] = *(const f32x4*)(gamma + oc0);
    be4[mf] = *(const f32x4*)(beta + oc0);
    sa4[mf] = *(const f32x4*)(sig_alpha + oc0);
    mp4[mf] = *(const f32x4*)(mu_p + oc0);
  }
#pragma unroll
  for (int nf = 0; nf < 8; ++nf) {
    int x = nf * 16 + l15;
    float muv = red[1024 + row * 128 + x];
    float invv = red[1280 + row * 128 + x];
    size_t paddr = (size_t)(b * HW_ + y * 128 + x) * 128;
    float s2 = 0.f, q2 = 0.f;
#pragma unroll
    for (int mf = 0; mf < 4; ++mf) {
      int oc0 = wm * 64 + mf * 16 + kg * 4;
      u16x4 ffv = *(const u16x4*)(ff_cl + paddr + oc0);
      u16x4 hiv = *(const u16x4*)(hinh_cl + paddr + oc0);
      u16x4 st;
#pragma unroll
      for (int j = 0; j < 4; ++j) {
        float c1 =
            (bf2f(f2bf(acc[mf][nf][j])) - muv) * invv * ga4[mf][j] + be4[mf][j];
        float r = fmaxf((sa4[mf][j] * bf2f(hiv[j]) + mp4[mf][j]) * c1, 0.f);
        float v = fmaxf(bf2f(ffv[j]) - r, 0.f);
        unsigned short bv = f2bf(v);
        float vr = bf2f(bv);
        s2 += vr;
        q2 = fmaf(vr, vr, q2);
        st[j] = bv;
      }
      *(u16x4*)(out + paddr + oc0) = st;
    }
    s2 += __shfl_xor(s2, 16);
    q2 += __shfl_xor(q2, 16);
    s2 += __shfl_xor(s2, 32);
    q2 += __shfl_xor(q2, 32);
    if (kg == 0) {
      red[(wm * 2 + row) * 128 + x] = s2;
      red[512 + (wm * 2 + row) * 128 + x] = q2;
    }
  }
  __syncthreads();
  // phase D: g2 LN stats = inhibited sums + (h_exc,h_inh) partials
  {
    int r2 = tid >> 7, x2 = tid & 127;
    float s = red[r2 * 128 + x2] + red[(2 + r2) * 128 + x2];
    float qq = red[512 + r2 * 128 + x2] + red[512 + (2 + r2) * 128 + x2];
    int pg = b * HW_ + (y0 + r2) * 128 + x2;
    s += ps12[pg];
    qq += pq12[pg];
    float m = s * (1.f / 384.f);
    float var = qq * (1.f / 384.f) - m * m;
    mu_o[pg] = m;
    inv_o[pg] = rsqrtf(var + 1e-5f);
  }
}

extern "C" void kernel_launch(void* const* d_in, const int* in_sizes, int n_in,
                              void* d_out, int out_size, void* d_ws,
                              size_t ws_size, hipStream_t stream) {
  const float* ff     = (const float*)d_in[0];
  const float* h_exc  = (const float*)d_in[1];
  const float* h_inh  = (const float*)d_in[2];
  const float* W_gain = (const float*)d_in[3];
  const float* b_gain = (const float*)d_in[4];
  const float* W_mix  = (const float*)d_in[5];
  const float* b_mix  = (const float*)d_in[6];
  const float* W_inh  = (const float*)d_in[7];
  const float* W_exc  = (const float*)d_in[8];
  const float* alpha  = (const float*)d_in[9];
  const float* mu_p   = (const float*)d_in[10];
  const float* kappa  = (const float*)d_in[11];
  const float* omega  = (const float*)d_in[12];
  const float* c1_g   = (const float*)d_in[13];
  const float* c1_b   = (const float*)d_in[14];
  const float* c2_g   = (const float*)d_in[15];
  const float* c2_b   = (const float*)d_in[16];

  float* w = (float*)d_ws;
  unsigned short* Wp_inh = (unsigned short*)w;  w += 401408;
  unsigned short* Wp_exc = (unsigned short*)w;  w += 401408;
  unsigned short* Ag     = (unsigned short*)w;  w += 24576;
  unsigned short* Am     = (unsigned short*)w;  w += 24576;
  float* rs     = w;  w += 256;
  float* sa     = w;  w += 128;    // sigmoid(alpha)
  float* mu1    = w;  w += NPIX_;
  float* inv1   = w;  w += NPIX_;
  float* mu2    = w;  w += NPIX_;
  float* inv2   = w;  w += NPIX_;
  float* mu_c2  = w;  w += NPIX_;
  float* inv_c2 = w;  w += NPIX_;
  float* ps12   = w;  w += NPIX_;
  float* pq12   = w;  w += NPIX_;
  unsigned short* exc_cl   = (unsigned short*)w;  w += 8388608;
  unsigned short* hinh_cl  = (unsigned short*)w;  w += 8388608;
  unsigned short* ffinh_cl = (unsigned short*)w;  w += 8388608;  // ff -> inhibited
  unsigned short* conv_cl  = (unsigned short*)w;  w += 8388608;  // c2raw

  unsigned short* gated_cl = (unsigned short*)d_out;  // dead before final write

  prep_w_bf16_k<<<3136, 256, 0, stream>>>(W_inh, W_exc, Wp_inh, Wp_exc);
  prep_apack_k<<<192, 256, 0, stream>>>(W_gain, W_mix, Ag, Am);
  rowsum_k<<<1, 256, 0, stream>>>(W_gain, W_mix, alpha, rs, sa);

  // g1 LN stats + channels-last bf16 copies + (h_exc,h_inh) partials for g2
  stats3_cvt_k<<<4096, 256, 0, stream>>>(h_exc, h_inh, ff, mu1, inv1, ps12,
                                         pq12, exc_cl, hinh_cl, ffinh_cl);
  // gated = h_exc * g1  (bf16 channels-last into d_out)
  {
    dim3 g(128, 8);
    gemm_mfma_k<0><<<g, 256, 0, stream>>>(
        Ag, rs, b_gain, exc_cl, hinh_cl, ffinh_cl, mu1, inv1, exc_cl, gated_cl,
        nullptr, nullptr, nullptr, nullptr, nullptr, nullptr, nullptr, nullptr,
        nullptr, nullptr);
  }
  // c1 = sym_conv(gated) with FUSED LN + inhibit + g2-stats epilogue.
  // Writes inhibited (in-place over ff_cl) and mu2/inv2 directly.
  conv7_mfma_k<1><<<512, 256, 0, stream>>>(gated_cl, Wp_inh, ffinh_cl, mu2,
                                           inv2, ffinh_cl, hinh_cl, ps12, pq12,
                                           sa, mu_p, c1_g, c1_b);
  // c2 = sym_conv(inhibited) + plain LN-stats epilogue
  conv7_mfma_k<0><<<512, 256, 0, stream>>>(ffinh_cl, Wp_exc, conv_cl, mu_c2,
                                           inv_c2, nullptr, nullptr, nullptr,
                                           nullptr, nullptr, nullptr, nullptr,
                                           nullptr);
  // g2 gemm + fused final mix -> d_out f32 NCHW
  {
    dim3 g(128, 8);
    gemm_mfma_k<1><<<g, 256, 0, stream>>>(
        Am, rs + 128, b_mix, ffinh_cl, exc_cl, hinh_cl, mu2, inv2, nullptr,
        nullptr, conv_cl, mu_c2, inv_c2, ffinh_cl, exc_cl, c2_g, c2_b, kappa,
        omega, (float*)d_out);
  }
}